// Round 11
// baseline (133.574 us; speedup 1.0000x reference)
//
#include <hip/hip_runtime.h>
#include <hip/hip_bf16.h>

#define H_Q 16
#define H_KV 4
#define HD 80
#define QKV_ROW 1920   // qkv buffer row stride (cols 0..1599 live: Q,K)
#define K_OFF 1280     // 16*80
#define EMB 1280
#define QT 128         // query tile rows (8 waves)
#define KC 64          // k/v chunk rows
#define KROW 104       // K_lds row stride (u16): 208B = 13x16B slots; fr*52dw = 8 bank-groups -> 2-way
#define VTS 4096       // v_t row stride (tokens)

typedef unsigned short u16;
typedef unsigned int u32;
typedef __attribute__((ext_vector_type(8))) short bf16x8;
typedef __attribute__((ext_vector_type(4))) float f32x4;
typedef __attribute__((ext_vector_type(16))) float f32x16;

__device__ inline u16 f2bf(float f) {
  unsigned u = __float_as_uint(f);
  unsigned r = (u + 0x7FFFu + ((u >> 16) & 1u)) >> 16;
  return (u16)r;
}
__device__ inline float bf2f(u16 v) { return __uint_as_float(((unsigned)v) << 16); }

__device__ inline void cvt4(const float* __restrict__ in, u16* __restrict__ out, int q) {
  float4 v = *reinterpret_cast<const float4*>(in + q * 4);
  ushort4 o;
  o.x = f2bf(v.x); o.y = f2bf(v.y); o.z = f2bf(v.z); o.w = f2bf(v.w);
  *reinterpret_cast<ushort4*>(out + q * 4) = o;
}

// ---------------- fused prep: 3x fp32->bf16 + seg ids ----------------
__global__ __launch_bounds__(256) void prep_kernel(const float* __restrict__ hidden,
                                                   const float* __restrict__ w_qkv,
                                                   const float* __restrict__ w_o,
                                                   const int* __restrict__ cu, int n_seq, int T,
                                                   u16* __restrict__ hid_bf,
                                                   u16* __restrict__ wqkv_bf,
                                                   u16* __restrict__ wo_bf,
                                                   int* __restrict__ seg,
                                                   int nq_hid, int nq_wqkv, int nq_wo) {
  const int i = blockIdx.x * 256 + threadIdx.x;
  if (i < T) {
    int s = 0;
    for (int k = 1; k <= n_seq; ++k) s += (i >= cu[k]) ? 1 : 0;
    seg[i] = s;
  }
  int q = i;
  if (q < nq_hid) { cvt4(hidden, hid_bf, q); return; }
  q -= nq_hid;
  if (q < nq_wqkv) { cvt4(w_qkv, wqkv_bf, q); return; }
  q -= nq_wqkv;
  if (q < nq_wo) cvt4(w_o, wo_bf, q);
}

// ---------------- bf16 MFMA GEMM: C[M,N] = A[M,K] * B[N,K]^T ----------------
// 128x128 tile, 4 waves, 32x32x16 MFMA (8 MFMA/K-step/wave vs 16 for 16x16x32;
// same ds_read count). 3 LDS buffers, prefetch distance 2, counted vmcnt.
// VSPLIT: column-fragments with col>=1600 are written TRANSPOSED to vt[col-1600][row].
template <typename OUT, bool VSPLIT>
__global__ __launch_bounds__(256) void gemm_bf16(const u16* __restrict__ A,
                                                 const u16* __restrict__ B,
                                                 OUT* __restrict__ C,
                                                 u16* __restrict__ vt,
                                                 int M, int N, int K, int ldc,
                                                 int gx, int nwg) {
  __shared__ u16 As[3][128 * 32];
  __shared__ u16 Bs[3][128 * 32];
  const int tid = threadIdx.x;
  const int id = blockIdx.x;
  const int sw = (id & 7) * (nwg >> 3) + (id >> 3);  // nwg % 8 == 0 guaranteed
  const int bm = (sw / gx) * 128;
  const int bn = (sw % gx) * 128;
  const int w = tid >> 6;
  const int l = tid & 63;
  const int wr = (w >> 1) * 64, wc = (w & 1) * 64;
  const int r32 = l & 31;        // row (A) / col (B,C) within 32-tile
  const int hk = (l >> 5) * 8;   // k sub-offset within a 16-half
  const int arow = tid >> 2, acol = (tid & 3) * 8;

  f32x16 acc[2][2];
  #pragma unroll
  for (int mi = 0; mi < 2; ++mi)
    #pragma unroll
    for (int ni = 0; ni < 2; ++ni)
      #pragma unroll
      for (int e = 0; e < 16; ++e) acc[mi][ni][e] = 0.f;

  // 4 global_load_lds (vmem ops) per thread per STAGE
  #define GSTAGE(buf, k0)                                                             \
    do {                                                                              \
      _Pragma("unroll")                                                               \
      for (int it = 0; it < 2; ++it) {                                                \
        const u16* ga = A + (size_t)(bm + it * 64 + arow) * K + (k0) + acol;          \
        __builtin_amdgcn_global_load_lds(                                             \
            (const __attribute__((address_space(1))) unsigned int*)ga,                \
            (__attribute__((address_space(3))) unsigned int*)&As[buf][it * 2048 + tid * 8], 16, 0, 0); \
        const u16* gb = B + (size_t)(bn + it * 64 + arow) * K + (k0) + acol;          \
        __builtin_amdgcn_global_load_lds(                                             \
            (const __attribute__((address_space(1))) unsigned int*)gb,                \
            (__attribute__((address_space(3))) unsigned int*)&Bs[buf][it * 2048 + tid * 8], 16, 0, 0); \
      }                                                                               \
    } while (0)

  const int nt = K >> 5;  // >= 2 for all our shapes (K=1280 -> 40)
  GSTAGE(0, 0);
  GSTAGE(1, 32);

  int cur = 0;
  for (int t = 0; t < nt; ++t) {
    if (t + 2 < nt) {
      const int nb = (cur + 2) % 3;
      GSTAGE(nb, (t + 2) * 32);
      asm volatile("s_waitcnt vmcnt(8)" ::: "memory");
    } else if (t + 1 < nt) {
      asm volatile("s_waitcnt vmcnt(4)" ::: "memory");
    } else {
      asm volatile("s_waitcnt vmcnt(0)" ::: "memory");
    }
    __builtin_amdgcn_s_barrier();           // all waves: buf[cur] DMA complete
    __builtin_amdgcn_sched_barrier(0);      // pin ds_reads after the wait

    bf16x8 af[2][2], bfr[2][2];
    #pragma unroll
    for (int mi = 0; mi < 2; ++mi)
      #pragma unroll
      for (int h = 0; h < 2; ++h)
        af[mi][h] = *reinterpret_cast<const bf16x8*>(
            &As[cur][(wr + mi * 32 + r32) * 32 + h * 16 + hk]);
    #pragma unroll
    for (int ni = 0; ni < 2; ++ni)
      #pragma unroll
      for (int h = 0; h < 2; ++h)
        bfr[ni][h] = *reinterpret_cast<const bf16x8*>(
            &Bs[cur][(wc + ni * 32 + r32) * 32 + h * 16 + hk]);
    __builtin_amdgcn_s_setprio(1);
    #pragma unroll
    for (int mi = 0; mi < 2; ++mi)
      #pragma unroll
      for (int ni = 0; ni < 2; ++ni)
        #pragma unroll
        for (int h = 0; h < 2; ++h)
          acc[mi][ni] = __builtin_amdgcn_mfma_f32_32x32x16_bf16(af[mi][h], bfr[ni][h],
                                                               acc[mi][ni], 0, 0, 0);
    __builtin_amdgcn_s_setprio(0);

    __builtin_amdgcn_sched_barrier(0);
    __builtin_amdgcn_s_barrier();           // all waves' reads of buf[cur] done
    cur = (cur + 1) % 3;
  }
  #undef GSTAGE

  // C/D layout (32x32, HW-verified): col = lane&31, row = (reg&3) + 8*(reg>>2) + 4*(lane>>5)
  #pragma unroll
  for (int mi = 0; mi < 2; ++mi)
    #pragma unroll
    for (int ni = 0; ni < 2; ++ni) {
      const int col = bn + wc + ni * 32 + r32;
      #pragma unroll
      for (int rq = 0; rq < 4; ++rq) {
        const int row0 = bm + wr + mi * 32 + 8 * rq + 4 * (l >> 5);
        if (VSPLIT && col >= 1600) {
          ushort4 o;
          o.x = f2bf(acc[mi][ni][rq * 4 + 0]); o.y = f2bf(acc[mi][ni][rq * 4 + 1]);
          o.z = f2bf(acc[mi][ni][rq * 4 + 2]); o.w = f2bf(acc[mi][ni][rq * 4 + 3]);
          *reinterpret_cast<ushort4*>(&vt[(size_t)(col - 1600) * VTS + row0]) = o;
        } else {
          #pragma unroll
          for (int j = 0; j < 4; ++j) {
            if constexpr (sizeof(OUT) == 2)
              C[(size_t)(row0 + j) * ldc + col] = f2bf(acc[mi][ni][rq * 4 + j]);
            else
              C[(size_t)(row0 + j) * ldc + col] = acc[mi][ni][rq * 4 + j];
          }
        }
      }
    }
}

// ---------------- per-token RMSNorm + RoPE ----------------
// grid = T, block 320 (5 waves); wave w handles heads w*4 .. w*4+3.
// NOTE: the rotate-half read xs[w][d +/- 40] is a CROSS-LANE dependency through
// LDS; __syncthreads() between write and read is REQUIRED (R6/R7 failure).
__global__ __launch_bounds__(320) void norm_rope_bf(u16* __restrict__ qkv,
                                                    const float* __restrict__ freqs,
                                                    const float* __restrict__ qw,
                                                    const float* __restrict__ kw) {
  const int t = blockIdx.x;
  const int tid = threadIdx.x;
  __shared__ float cs[HD], sn[HD];
  __shared__ float wq[HD], wk[HD];
  __shared__ float xs[5][HD];
  if (tid < HD) {
    const float f = freqs[(size_t)t * HD + tid];
    cs[tid] = __cosf(f);
    sn[tid] = __sinf(f);
    wq[tid] = qw[tid];
    wk[tid] = kw[tid];
  }
  __syncthreads();
  const int w = tid >> 6, lane = tid & 63;
  #pragma unroll
  for (int i = 0; i < 4; ++i) {
    const int hh = w * 4 + i;
    const bool is_q = (hh < H_Q);
    u16* x = qkv + (size_t)t * QKV_ROW + (is_q ? hh * HD : K_OFF + (hh - H_Q) * HD);
    const float* wt = is_q ? wq : wk;
    float a = bf2f(x[lane]);
    float b = (lane < HD - 64) ? bf2f(x[64 + lane]) : 0.0f;
    float ss = a * a + b * b;
    #pragma unroll
    for (int off = 32; off; off >>= 1) ss += __shfl_down(ss, off);
    ss = __shfl(ss, 0);
    const float inv = rsqrtf(ss * (1.0f / HD) + 1e-6f);
    xs[w][lane] = a * inv * wt[lane];
    if (lane < HD - 64) xs[w][64 + lane] = b * inv * wt[64 + lane];
    __syncthreads();  // REQUIRED: cross-lane LDS dep
    {
      const int d = lane;
      const float rot = (d < HD / 2) ? -xs[w][d + HD / 2] : xs[w][d - HD / 2];
      x[d] = f2bf(xs[w][d] * cs[d] + rot * sn[d]);
    }
    if (lane < HD - 64) {
      const int d = 64 + lane;
      const float rot = (d < HD / 2) ? -xs[w][d + HD / 2] : xs[w][d - HD / 2];
      x[d] = f2bf(xs[w][d] * cs[d] + rot * sn[d]);
    }
    __syncthreads();  // all reads done before next iteration's writes
  }
}

// ---------------- MFMA flash attention v7 ----------------
// grid (T/QT, 16), 8 waves. Swapped QK^T (S^T = mfma(K, Q)): lane (g,fr) holds
// P[k=f*16+g*4+j][q=fr] -> P stays in registers; cvt_pk to bf16 and a per-wave
// LDS exchange builds PV's A-fragments. K_lds stride 104 (2-way banks on QK reads;
// pad cols 80..103 filled from adjacent finite qkv data via 13-slot staging).
// No online max (RMSNorm bounds |S*scale| <= ~9.0 -> exp2 <= 8.2e3, finite).
// l-sum free via ones-row MFMA.
__global__ __launch_bounds__(512) void attn_v7(const u16* __restrict__ qkv,
                                               const u16* __restrict__ vt,
                                               const int* __restrict__ seg,
                                               const int* __restrict__ cu,
                                               int T,
                                               u16* __restrict__ attn_bf) {
  __shared__ u16 K_lds[2][KC * KROW];       // [k][e] stride 104; cols 80..103 pad (finite)
  __shared__ u16 V_lds[2][96 * 64];         // V^T rows 0..79 staged; 80=ones, 81..95=0
  __shared__ u32 Pw[8][16 * 36];            // per-wave P exchange: fr stride 36 u32
  __shared__ int ksegs[2][KC];

  const int t0 = blockIdx.x * QT;
  const int h = blockIdx.y;
  const int kvh = h >> 2;
  const int tid = threadIdx.x;
  const int w = tid >> 6, l = tid & 63;
  const int g = l >> 4, fr = l & 15;

  for (int i = tid; i < 2 * 16 * 32; i += 512) {
    const int b = i >> 9, r = (i >> 5) & 15, c = i & 31;
    ((u32*)V_lds[b])[(80 + r) * 32 + c] = (r == 0) ? 0x3f803f80u : 0u;
  }

  const int s0_ = seg[t0], s1_ = seg[t0 + QT - 1];
  const int kbeg = cu[s0_], kend = cu[s1_ + 1];
  const bool fast = (s0_ == s1_) && (((kend - kbeg) & (KC - 1)) == 0) && ((kbeg & 7) == 0);

  // Q fragments (registers). head-dim padded 80->96 with zeros.
  const int qrow = t0 + w * 16 + fr;
  const u16* qp = qkv + (size_t)qrow * QKV_ROW + h * HD;
  bf16x8 qa0 = *reinterpret_cast<const bf16x8*>(qp + g * 8);
  bf16x8 qa1 = *reinterpret_cast<const bf16x8*>(qp + 32 + g * 8);
  bf16x8 qa2 = (g < 2) ? *reinterpret_cast<const bf16x8*>(qp + 64 + g * 8)
                       : (bf16x8)(short)0;
  const int qsgl = seg[qrow];  // swapped layout: lane's q-row is fr-based

  f32x4 acc[6];
  #pragma unroll
  for (int dt = 0; dt < 6; ++dt) acc[dt] = (f32x4){0.f, 0.f, 0.f, 0.f};
  const float C2 = 0.16130010464f;  // (1/sqrt(80)) * log2(e)

  // fast stage: K rows as 13x16B slots (incl. finite pad from adjacent qkv cols);
  // V^T rows with inverse-XOR'd source.
  #define ASTAGE(nb, cc)                                                               \
    do {                                                                               \
      for (int i = tid; i < 832; i += 512) {                                           \
        const int kr = i / 13, ks_ = i - kr * 13;                                      \
        const u16* gk = qkv + (size_t)((cc) + kr) * QKV_ROW + K_OFF + kvh * HD + ks_ * 8; \
        __builtin_amdgcn_global_load_lds(                                              \
            (const __attribute__((address_space(1))) u32*)gk,                          \
            (__attribute__((address_space(3))) u32*)&K_lds[nb][i * 8], 16, 0, 0);      \
      }                                                                                \
      for (int i = tid; i < 640; i += 512) {                                           \
        const int vr = i >> 3, vs = i & 7;                                             \
        const u16* gv = vt + (size_t)(kvh * HD + vr) * VTS + (cc) + ((vs ^ (vr & 7)) * 8); \
        __builtin_amdgcn_global_load_lds(                                              \
            (const __attribute__((address_space(1))) u32*)gv,                          \
            (__attribute__((address_space(3))) u32*)&V_lds[nb][i * 8], 16, 0, 0);      \
      }                                                                                \
    } while (0)

  #define SSTAGE(nb, cc)                                                               \
    do {                                                                               \
      for (int i = tid; i < KC * 52; i += 512) {                                       \
        const int r = i / 52, ccc = i - r * 52;                                        \
        u32 v = 0;                                                                     \
        if (ccc < 40 && (cc) + r < kend)                                               \
          v = reinterpret_cast<const u32*>(qkv + (size_t)((cc) + r) * QKV_ROW + K_OFF + kvh * HD)[ccc]; \
        ((u32*)K_lds[nb])[i] = v;                                                      \
      }                                                                                \
      for (int i = tid; i < HD * KC; i += 512) {                                       \
        const int vr = i >> 6, k = i & 63;                                             \
        u16 v = 0;                                                                     \
        if ((cc) + k < kend)                                                           \
          v = vt[(size_t)(kvh * HD + vr) * VTS + (cc) + k];                            \
        V_lds[nb][vr * 64 + (((k >> 3) ^ (vr & 7)) * 8) + (k & 7)] = v;                \
      }                                                                                \
      if (tid < KC) ksegs[nb][tid] = ((cc) + tid < kend) ? seg[(cc) + tid] : -1;       \
    } while (0)

  if (fast) ASTAGE(0, kbeg); else SSTAGE(0, kbeg);
  __syncthreads();

  const int c3 = (fr & 3) << 2;       // pair-granularity XOR swizzle key
  u32* pw = &Pw[w][0];
  const int sA = 4 * (g >> 1) + 2 * (g & 1);

  int nb = 0;
  for (int c = kbeg; c < kend; c += KC) {
    const int cur = nb;
    nb ^= 1;
    if (c + KC < kend) {
      if (fast) ASTAGE(nb, c + KC); else SSTAGE(nb, c + KC);
    }

    // ---- S^T = K Q^T (swapped operands) ----
    const u16* kb = K_lds[cur];
    f32x4 sacc[4];
    #pragma unroll
    for (int f = 0; f < 4; ++f) {
      const u16* kp = kb + (f * 16 + fr) * KROW;
      bf16x8 b0 = *reinterpret_cast<const bf16x8*>(kp + g * 8);
      bf16x8 b1 = *reinterpret_cast<const bf16x8*>(kp + 32 + g * 8);
      bf16x8 b2 = *reinterpret_cast<const bf16x8*>(kp + 64 + g * 8);  // cols 80..95 pad: finite, A=0
      f32x4 s = (f32x4){0.f, 0.f, 0.f, 0.f};
      s = __builtin_amdgcn_mfma_f32_16x16x32_bf16(b0, qa0, s, 0, 0, 0);
      s = __builtin_amdgcn_mfma_f32_16x16x32_bf16(b1, qa1, s, 0, 0, 0);
      s = __builtin_amdgcn_mfma_f32_16x16x32_bf16(b2, qa2, s, 0, 0, 0);
      sacc[f] = s;  // sacc[f][j] = S[k = c + f*16 + g*4 + j][q = fr]
    }

    // ---- P = exp2(S*C2), cvt_pk to bf16, wave-local LDS exchange ----
    if (fast) {
      #pragma unroll
      for (int f = 0; f < 4; ++f) {
        const float p0 = __builtin_exp2f(sacc[f][0] * C2);
        const float p1 = __builtin_exp2f(sacc[f][1] * C2);
        const float p2 = __builtin_exp2f(sacc[f][2] * C2);
        const float p3 = __builtin_exp2f(sacc[f][3] * C2);
        u32 lo, hi;
        asm("v_cvt_pk_bf16_f32 %0, %1, %2" : "=v"(lo) : "v"(p0), "v"(p1));
        asm("v_cvt_pk_bf16_f32 %0, %1, %2" : "=v"(hi) : "v"(p2), "v"(p3));
        const int sel = (4 * f + g) ^ c3;
        *reinterpret_cast<uint2*>(&pw[fr * 36 + sel * 2]) = make_uint2(lo, hi);
      }
    } else {
      #pragma unroll
      for (int f = 0; f < 4; ++f) {
        float pj[4];
        #pragma unroll
        for (int j = 0; j < 4; ++j) {
          const int kk = f * 16 + g * 4 + j;
          float e = sacc[f][j] * C2;
          if (qsgl != ksegs[cur][kk]) e = -1e30f;  // exp2(-inf) = 0
          pj[j] = __builtin_exp2f(e);
        }
        u32 lo, hi;
        asm("v_cvt_pk_bf16_f32 %0, %1, %2" : "=v"(lo) : "v"(pj[0]), "v"(pj[1]));
        asm("v_cvt_pk_bf16_f32 %0, %1, %2" : "=v"(hi) : "v"(pj[2]), "v"(pj[3]));
        const int sel = (4 * f + g) ^ c3;
        *reinterpret_cast<uint2*>(&pw[fr * 36 + sel * 2]) = make_uint2(lo, hi);
      }
    }
    // cross-lane LDS dep within the wave: drain DS writes, pin reads after
    asm volatile("s_waitcnt lgkmcnt(0)" ::: "memory");
    __builtin_amdgcn_sched_barrier(0);
    bf16x8 pa0 = *reinterpret_cast<const bf16x8*>(&pw[fr * 36 + ((sA ^ c3) * 2)]);
    bf16x8 pa1 = *reinterpret_cast<const bf16x8*>(&pw[fr * 36 + (((8 + sA) ^ c3) * 2)]);

    // ---- PV (+ ones-row l-sum in dt=5), swizzled V reads ----
    const u16* vb = V_lds[cur];
    #pragma unroll
    for (int dt = 0; dt < 6; ++dt) {
      const int row = dt * 16 + fr;
      const u16* vp = vb + row * 64;
      bf16x8 vb0 = *reinterpret_cast<const bf16x8*>(vp + ((g ^ (fr & 7)) * 8));
      bf16x8 vb1 = *reinterpret_cast<const bf16x8*>(vp + ((((4 + g)) ^ (fr & 7)) * 8));
      acc[dt] = __builtin_amdgcn_mfma_f32_16x16x32_bf16(pa0, vb0, acc[dt], 0, 0, 0);
      acc[dt] = __builtin_amdgcn_mfma_f32_16x16x32_bf16(pa1, vb1, acc[dt], 0, 0, 0);
    }

    __syncthreads();
  }
  #undef ASTAGE
  #undef SSTAGE

  // ---- epilogue (acc[dt][j] = O[q-row g*4+j][d=dt*16+fr]) ----
  #pragma unroll
  for (int j = 0; j < 4; ++j) {
    const float lsum = __shfl(acc[5][j], l & 48);  // lane (g, fr=0): ones-row sum
    const float il = (lsum > 0.f) ? 1.0f / lsum : 0.f;
    const int row = t0 + w * 16 + g * 4 + j;
    #pragma unroll
    for (int dt = 0; dt < 5; ++dt)
      attn_bf[(size_t)row * EMB + h * HD + dt * 16 + fr] = f2bf(acc[dt][j] * il);
  }
}

extern "C" void kernel_launch(void* const* d_in, const int* in_sizes, int n_in,
                              void* d_out, int out_size, void* d_ws, size_t ws_size,
                              hipStream_t stream) {
  const float* hidden = (const float*)d_in[0];
  const int*   cu     = (const int*)d_in[1];
  const float* rope   = (const float*)d_in[2];
  const float* w_qkv  = (const float*)d_in[3];
  const float* w_o    = (const float*)d_in[4];
  const float* qw     = (const float*)d_in[5];
  const float* kw     = (const float*)d_in[6];
  float* out = (float*)d_out;

  const int T = in_sizes[0] / EMB;   // 4096
  const int n_seq = in_sizes[1] - 1; // 8

  // workspace (~37MB): qkv_bf | hid_bf(=attn_bf alias) | wqkv_bf | wo_bf | v_t | seg
  u16* qkv_bf  = (u16*)d_ws;
  u16* hid_bf  = qkv_bf + (size_t)T * QKV_ROW;
  u16* attn_bf = hid_bf;  // alias: hid_bf dead after gemm_qkv
  u16* wqkv_bf = hid_bf + (size_t)T * EMB;
  u16* wo_bf   = wqkv_bf + (size_t)QKV_ROW * EMB;
  u16* v_t     = wo_bf + (size_t)EMB * EMB;           // [320][4096] + slack
  int* segb    = (int*)(v_t + (size_t)320 * 4096 + 64);

  const int nq_hid = T * EMB / 4, nq_wqkv = QKV_ROW * EMB / 4, nq_wo = EMB * EMB / 4;
  const int nq_tot = nq_hid + nq_wqkv + nq_wo;
  prep_kernel<<<(nq_tot + 255) / 256, 256, 0, stream>>>(
      hidden, w_qkv, w_o, cu, n_seq, T, hid_bf, wqkv_bf, wo_bf, segb,
      nq_hid, nq_wqkv, nq_wo);

  // qkv[:,0:1600] + v_t = hidden @ w_qkv^T  (V columns transposed; grid 480 % 8 == 0)
  {
    const int gx = 15, nwg = gx * (T / 128);  // 480
    gemm_bf16<u16, true><<<nwg, 256, 0, stream>>>(hid_bf, wqkv_bf, qkv_bf, v_t,
                                                  T, QKV_ROW, EMB, QKV_ROW, gx, nwg);
  }
  norm_rope_bf<<<T, 320, 0, stream>>>(qkv_bf, rope, qw, kw);
  attn_v7<<<dim3(T / QT, H_Q), 512, 0, stream>>>(qkv_bf, v_t, segb, cu, T, attn_bf);
  // out = attn @ w_o^T  (fp32 out; grid 320 % 8 == 0)
  {
    const int gx = 10, nwg = gx * (T / 128);  // 320
    gemm_bf16<float, false><<<nwg, 256, 0, stream>>>(attn_bf, wo_bf, out, nullptr,
                                                     T, EMB, EMB, EMB, gx, nwg);
  }
}

// Round 12
// 123.850 us; speedup vs baseline: 1.0785x; 1.0785x over previous
//
#include <hip/hip_runtime.h>
#include <hip/hip_bf16.h>

#define H_Q 16
#define H_KV 4
#define HD 80
#define QKV_ROW 1920   // qkv buffer row stride (cols 0..1599 live: Q,K)
#define K_OFF 1280     // 16*80
#define EMB 1280
#define QT 128         // query tile rows (8 waves)
#define KC 64          // k/v chunk rows
#define KROW 104       // K_lds row stride (u16): 208B = 13x16B slots; 2-way banks on QK reads
#define VTS 4096       // v_t row stride (tokens)

typedef unsigned short u16;
typedef unsigned int u32;
typedef __attribute__((ext_vector_type(8))) short bf16x8;
typedef __attribute__((ext_vector_type(4))) float f32x4;
typedef __attribute__((ext_vector_type(16))) float f32x16;

__device__ inline u16 f2bf(float f) {
  unsigned u = __float_as_uint(f);
  unsigned r = (u + 0x7FFFu + ((u >> 16) & 1u)) >> 16;
  return (u16)r;
}
__device__ inline float bf2f(u16 v) { return __uint_as_float(((unsigned)v) << 16); }

__device__ inline void cvt4(const float* __restrict__ in, u16* __restrict__ out, int q) {
  float4 v = *reinterpret_cast<const float4*>(in + q * 4);
  ushort4 o;
  o.x = f2bf(v.x); o.y = f2bf(v.y); o.z = f2bf(v.z); o.w = f2bf(v.w);
  *reinterpret_cast<ushort4*>(out + q * 4) = o;
}

// ---------------- fused prep: 3x fp32->bf16 + seg ids ----------------
__global__ __launch_bounds__(256) void prep_kernel(const float* __restrict__ hidden,
                                                   const float* __restrict__ w_qkv,
                                                   const float* __restrict__ w_o,
                                                   const int* __restrict__ cu, int n_seq, int T,
                                                   u16* __restrict__ hid_bf,
                                                   u16* __restrict__ wqkv_bf,
                                                   u16* __restrict__ wo_bf,
                                                   int* __restrict__ seg,
                                                   int nq_hid, int nq_wqkv, int nq_wo) {
  const int i = blockIdx.x * 256 + threadIdx.x;
  if (i < T) {
    int s = 0;
    for (int k = 1; k <= n_seq; ++k) s += (i >= cu[k]) ? 1 : 0;
    seg[i] = s;
  }
  int q = i;
  if (q < nq_hid) { cvt4(hidden, hid_bf, q); return; }
  q -= nq_hid;
  if (q < nq_wqkv) { cvt4(w_qkv, wqkv_bf, q); return; }
  q -= nq_wqkv;
  if (q < nq_wo) cvt4(w_o, wo_bf, q);
}

// ---------------- bf16 MFMA GEMM: C[M,N] = A[M,K] * B[N,K]^T ----------------
// 128x128 tile, 4 waves, 32x32x16 MFMA (8 MFMA/K-step/wave). K-slot XOR swizzle
// (T21 both-sides): physical slot p of row r holds logical slot p^((r>>1)&3);
// global source pre-swizzled, reads apply same XOR -> 2 lanes/bank (conflict-free;
// R11's linear layout was 4-way). 3 LDS buffers, prefetch distance 2, counted vmcnt.
// VSPLIT: column-fragments with col>=1600 are written TRANSPOSED to vt[col-1600][row].
template <typename OUT, bool VSPLIT>
__global__ __launch_bounds__(256) void gemm_bf16(const u16* __restrict__ A,
                                                 const u16* __restrict__ B,
                                                 OUT* __restrict__ C,
                                                 u16* __restrict__ vt,
                                                 int M, int N, int K, int ldc,
                                                 int gx, int nwg) {
  __shared__ u16 As[3][128 * 32];
  __shared__ u16 Bs[3][128 * 32];
  const int tid = threadIdx.x;
  const int id = blockIdx.x;
  const int sw = (id & 7) * (nwg >> 3) + (id >> 3);  // nwg % 8 == 0 guaranteed
  const int bm = (sw / gx) * 128;
  const int bn = (sw % gx) * 128;
  const int w = tid >> 6;
  const int l = tid & 63;
  const int wr = (w >> 1) * 64, wc = (w & 1) * 64;
  const int r32 = l & 31;        // row (A) / col (B,C) within 32-tile
  const int arow = tid >> 2;
  const int aslot = ((tid & 3) ^ ((tid >> 3) & 3)) * 8;  // pre-swizzled source k-slot

  f32x16 acc[2][2];
  #pragma unroll
  for (int mi = 0; mi < 2; ++mi)
    #pragma unroll
    for (int ni = 0; ni < 2; ++ni)
      #pragma unroll
      for (int e = 0; e < 16; ++e) acc[mi][ni][e] = 0.f;

  // 4 global_load_lds (vmem ops) per thread per STAGE; LDS dest linear (tid*16B),
  // source column swizzled (same 64B row segment -> coalescing unchanged).
  #define GSTAGE(buf, k0)                                                             \
    do {                                                                              \
      _Pragma("unroll")                                                               \
      for (int it = 0; it < 2; ++it) {                                                \
        const u16* ga = A + (size_t)(bm + it * 64 + arow) * K + (k0) + aslot;         \
        __builtin_amdgcn_global_load_lds(                                             \
            (const __attribute__((address_space(1))) unsigned int*)ga,                \
            (__attribute__((address_space(3))) unsigned int*)&As[buf][it * 2048 + tid * 8], 16, 0, 0); \
        const u16* gb = B + (size_t)(bn + it * 64 + arow) * K + (k0) + aslot;         \
        __builtin_amdgcn_global_load_lds(                                             \
            (const __attribute__((address_space(1))) unsigned int*)gb,                \
            (__attribute__((address_space(3))) unsigned int*)&Bs[buf][it * 2048 + tid * 8], 16, 0, 0); \
      }                                                                               \
    } while (0)

  const int nt = K >> 5;  // >= 2 for all our shapes (K=1280 -> 40)
  GSTAGE(0, 0);
  GSTAGE(1, 32);

  const int rsw = (l >> 1) & 3;  // read-side XOR key = row bits 1..2
  int cur = 0;
  for (int t = 0; t < nt; ++t) {
    if (t + 2 < nt) {
      const int nb = (cur + 2) % 3;
      GSTAGE(nb, (t + 2) * 32);
      asm volatile("s_waitcnt vmcnt(8)" ::: "memory");
    } else if (t + 1 < nt) {
      asm volatile("s_waitcnt vmcnt(4)" ::: "memory");
    } else {
      asm volatile("s_waitcnt vmcnt(0)" ::: "memory");
    }
    __builtin_amdgcn_s_barrier();           // all waves: buf[cur] DMA complete
    __builtin_amdgcn_sched_barrier(0);      // pin ds_reads after the wait

    bf16x8 af[2][2], bfr[2][2];
    #pragma unroll
    for (int mi = 0; mi < 2; ++mi)
      #pragma unroll
      for (int h = 0; h < 2; ++h) {
        const int ps = ((2 * h + (l >> 5)) ^ rsw) * 8;  // swizzled physical slot
        af[mi][h] = *reinterpret_cast<const bf16x8*>(
            &As[cur][(wr + mi * 32 + r32) * 32 + ps]);
      }
    #pragma unroll
    for (int ni = 0; ni < 2; ++ni)
      #pragma unroll
      for (int h = 0; h < 2; ++h) {
        const int ps = ((2 * h + (l >> 5)) ^ rsw) * 8;
        bfr[ni][h] = *reinterpret_cast<const bf16x8*>(
            &Bs[cur][(wc + ni * 32 + r32) * 32 + ps]);
      }
    __builtin_amdgcn_s_setprio(1);
    #pragma unroll
    for (int mi = 0; mi < 2; ++mi)
      #pragma unroll
      for (int ni = 0; ni < 2; ++ni)
        #pragma unroll
        for (int h = 0; h < 2; ++h)
          acc[mi][ni] = __builtin_amdgcn_mfma_f32_32x32x16_bf16(af[mi][h], bfr[ni][h],
                                                               acc[mi][ni], 0, 0, 0);
    __builtin_amdgcn_s_setprio(0);

    __builtin_amdgcn_sched_barrier(0);
    __builtin_amdgcn_s_barrier();           // all waves' reads of buf[cur] done
    cur = (cur + 1) % 3;
  }
  #undef GSTAGE

  // C/D layout (32x32, HW-verified): col = lane&31, row = (reg&3) + 8*(reg>>2) + 4*(lane>>5)
  #pragma unroll
  for (int mi = 0; mi < 2; ++mi)
    #pragma unroll
    for (int ni = 0; ni < 2; ++ni) {
      const int col = bn + wc + ni * 32 + r32;
      #pragma unroll
      for (int rq = 0; rq < 4; ++rq) {
        const int row0 = bm + wr + mi * 32 + 8 * rq + 4 * (l >> 5);
        if (VSPLIT && col >= 1600) {
          ushort4 o;
          o.x = f2bf(acc[mi][ni][rq * 4 + 0]); o.y = f2bf(acc[mi][ni][rq * 4 + 1]);
          o.z = f2bf(acc[mi][ni][rq * 4 + 2]); o.w = f2bf(acc[mi][ni][rq * 4 + 3]);
          *reinterpret_cast<ushort4*>(&vt[(size_t)(col - 1600) * VTS + row0]) = o;
        } else {
          #pragma unroll
          for (int j = 0; j < 4; ++j) {
            if constexpr (sizeof(OUT) == 2)
              C[(size_t)(row0 + j) * ldc + col] = f2bf(acc[mi][ni][rq * 4 + j]);
            else
              C[(size_t)(row0 + j) * ldc + col] = acc[mi][ni][rq * 4 + j];
          }
        }
      }
    }
}

// ---------------- per-token RMSNorm + RoPE ----------------
// grid = T, block 320 (5 waves); wave w handles heads w*4 .. w*4+3.
// NOTE: the rotate-half read xs[w][d +/- 40] is a CROSS-LANE dependency through
// LDS; __syncthreads() between write and read is REQUIRED (R6/R7 failure).
__global__ __launch_bounds__(320) void norm_rope_bf(u16* __restrict__ qkv,
                                                    const float* __restrict__ freqs,
                                                    const float* __restrict__ qw,
                                                    const float* __restrict__ kw) {
  const int t = blockIdx.x;
  const int tid = threadIdx.x;
  __shared__ float cs[HD], sn[HD];
  __shared__ float wq[HD], wk[HD];
  __shared__ float xs[5][HD];
  if (tid < HD) {
    const float f = freqs[(size_t)t * HD + tid];
    cs[tid] = __cosf(f);
    sn[tid] = __sinf(f);
    wq[tid] = qw[tid];
    wk[tid] = kw[tid];
  }
  __syncthreads();
  const int w = tid >> 6, lane = tid & 63;
  #pragma unroll
  for (int i = 0; i < 4; ++i) {
    const int hh = w * 4 + i;
    const bool is_q = (hh < H_Q);
    u16* x = qkv + (size_t)t * QKV_ROW + (is_q ? hh * HD : K_OFF + (hh - H_Q) * HD);
    const float* wt = is_q ? wq : wk;
    float a = bf2f(x[lane]);
    float b = (lane < HD - 64) ? bf2f(x[64 + lane]) : 0.0f;
    float ss = a * a + b * b;
    #pragma unroll
    for (int off = 32; off; off >>= 1) ss += __shfl_down(ss, off);
    ss = __shfl(ss, 0);
    const float inv = rsqrtf(ss * (1.0f / HD) + 1e-6f);
    xs[w][lane] = a * inv * wt[lane];
    if (lane < HD - 64) xs[w][64 + lane] = b * inv * wt[64 + lane];
    __syncthreads();  // REQUIRED: cross-lane LDS dep
    {
      const int d = lane;
      const float rot = (d < HD / 2) ? -xs[w][d + HD / 2] : xs[w][d - HD / 2];
      x[d] = f2bf(xs[w][d] * cs[d] + rot * sn[d]);
    }
    if (lane < HD - 64) {
      const int d = 64 + lane;
      const float rot = (d < HD / 2) ? -xs[w][d + HD / 2] : xs[w][d - HD / 2];
      x[d] = f2bf(xs[w][d] * cs[d] + rot * sn[d]);
    }
    __syncthreads();  // all reads done before next iteration's writes
  }
}

// ---------------- MFMA flash attention v7 ----------------
// grid (T/QT, 16), 8 waves. Swapped QK^T (S^T = mfma(K, Q)): lane (g,fr) holds
// P[k=f*16+g*4+j][q=fr] -> P stays in registers; cvt_pk to bf16 and a per-wave
// LDS exchange builds PV's A-fragments. K_lds stride 104 (2-way banks on QK reads;
// pad cols 80..103 filled from adjacent finite qkv data via 13-slot staging).
// No online max (RMSNorm bounds |S*scale| <= ~9.0 -> exp2 <= 8.2e3, finite).
// l-sum free via ones-row MFMA.
__global__ __launch_bounds__(512) void attn_v7(const u16* __restrict__ qkv,
                                               const u16* __restrict__ vt,
                                               const int* __restrict__ seg,
                                               const int* __restrict__ cu,
                                               int T,
                                               u16* __restrict__ attn_bf) {
  __shared__ u16 K_lds[2][KC * KROW];       // [k][e] stride 104; cols 80..103 pad (finite)
  __shared__ u16 V_lds[2][96 * 64];         // V^T rows 0..79 staged; 80=ones, 81..95=0
  __shared__ u32 Pw[8][16 * 36];            // per-wave P exchange: fr stride 36 u32
  __shared__ int ksegs[2][KC];

  const int t0 = blockIdx.x * QT;
  const int h = blockIdx.y;
  const int kvh = h >> 2;
  const int tid = threadIdx.x;
  const int w = tid >> 6, l = tid & 63;
  const int g = l >> 4, fr = l & 15;

  for (int i = tid; i < 2 * 16 * 32; i += 512) {
    const int b = i >> 9, r = (i >> 5) & 15, c = i & 31;
    ((u32*)V_lds[b])[(80 + r) * 32 + c] = (r == 0) ? 0x3f803f80u : 0u;
  }

  const int s0_ = seg[t0], s1_ = seg[t0 + QT - 1];
  const int kbeg = cu[s0_], kend = cu[s1_ + 1];
  const bool fast = (s0_ == s1_) && (((kend - kbeg) & (KC - 1)) == 0) && ((kbeg & 7) == 0);

  // Q fragments (registers). head-dim padded 80->96 with zeros.
  const int qrow = t0 + w * 16 + fr;
  const u16* qp = qkv + (size_t)qrow * QKV_ROW + h * HD;
  bf16x8 qa0 = *reinterpret_cast<const bf16x8*>(qp + g * 8);
  bf16x8 qa1 = *reinterpret_cast<const bf16x8*>(qp + 32 + g * 8);
  bf16x8 qa2 = (g < 2) ? *reinterpret_cast<const bf16x8*>(qp + 64 + g * 8)
                       : (bf16x8)(short)0;
  const int qsgl = seg[qrow];  // swapped layout: lane's q-row is fr-based

  f32x4 acc[6];
  #pragma unroll
  for (int dt = 0; dt < 6; ++dt) acc[dt] = (f32x4){0.f, 0.f, 0.f, 0.f};
  const float C2 = 0.16130010464f;  // (1/sqrt(80)) * log2(e)

  // fast stage: K rows as 13x16B slots (incl. finite pad from adjacent qkv cols);
  // V^T rows with inverse-XOR'd source.
  #define ASTAGE(nb, cc)                                                               \
    do {                                                                               \
      for (int i = tid; i < 832; i += 512) {                                           \
        const int kr = i / 13, ks_ = i - kr * 13;                                      \
        const u16* gk = qkv + (size_t)((cc) + kr) * QKV_ROW + K_OFF + kvh * HD + ks_ * 8; \
        __builtin_amdgcn_global_load_lds(                                              \
            (const __attribute__((address_space(1))) u32*)gk,                          \
            (__attribute__((address_space(3))) u32*)&K_lds[nb][i * 8], 16, 0, 0);      \
      }                                                                                \
      for (int i = tid; i < 640; i += 512) {                                           \
        const int vr = i >> 3, vs = i & 7;                                             \
        const u16* gv = vt + (size_t)(kvh * HD + vr) * VTS + (cc) + ((vs ^ (vr & 7)) * 8); \
        __builtin_amdgcn_global_load_lds(                                              \
            (const __attribute__((address_space(1))) u32*)gv,                          \
            (__attribute__((address_space(3))) u32*)&V_lds[nb][i * 8], 16, 0, 0);      \
      }                                                                                \
    } while (0)

  #define SSTAGE(nb, cc)                                                               \
    do {                                                                               \
      for (int i = tid; i < KC * 52; i += 512) {                                       \
        const int r = i / 52, ccc = i - r * 52;                                        \
        u32 v = 0;                                                                     \
        if (ccc < 40 && (cc) + r < kend)                                               \
          v = reinterpret_cast<const u32*>(qkv + (size_t)((cc) + r) * QKV_ROW + K_OFF + kvh * HD)[ccc]; \
        ((u32*)K_lds[nb])[i] = v;                                                      \
      }                                                                                \
      for (int i = tid; i < HD * KC; i += 512) {                                       \
        const int vr = i >> 6, k = i & 63;                                             \
        u16 v = 0;                                                                     \
        if ((cc) + k < kend)                                                           \
          v = vt[(size_t)(kvh * HD + vr) * VTS + (cc) + k];                            \
        V_lds[nb][vr * 64 + (((k >> 3) ^ (vr & 7)) * 8) + (k & 7)] = v;                \
      }                                                                                \
      if (tid < KC) ksegs[nb][tid] = ((cc) + tid < kend) ? seg[(cc) + tid] : -1;       \
    } while (0)

  if (fast) ASTAGE(0, kbeg); else SSTAGE(0, kbeg);
  __syncthreads();

  const int c3 = (fr & 3) << 2;       // pair-granularity XOR swizzle key
  u32* pw = &Pw[w][0];
  const int sA = 4 * (g >> 1) + 2 * (g & 1);

  int nb = 0;
  for (int c = kbeg; c < kend; c += KC) {
    const int cur = nb;
    nb ^= 1;
    if (c + KC < kend) {
      if (fast) ASTAGE(nb, c + KC); else SSTAGE(nb, c + KC);
    }

    // ---- S^T = K Q^T (swapped operands) ----
    const u16* kb = K_lds[cur];
    f32x4 sacc[4];
    #pragma unroll
    for (int f = 0; f < 4; ++f) {
      const u16* kp = kb + (f * 16 + fr) * KROW;
      bf16x8 b0 = *reinterpret_cast<const bf16x8*>(kp + g * 8);
      bf16x8 b1 = *reinterpret_cast<const bf16x8*>(kp + 32 + g * 8);
      bf16x8 b2 = *reinterpret_cast<const bf16x8*>(kp + 64 + g * 8);  // cols 80..95 pad: finite, A=0
      f32x4 s = (f32x4){0.f, 0.f, 0.f, 0.f};
      s = __builtin_amdgcn_mfma_f32_16x16x32_bf16(b0, qa0, s, 0, 0, 0);
      s = __builtin_amdgcn_mfma_f32_16x16x32_bf16(b1, qa1, s, 0, 0, 0);
      s = __builtin_amdgcn_mfma_f32_16x16x32_bf16(b2, qa2, s, 0, 0, 0);
      sacc[f] = s;  // sacc[f][j] = S[k = c + f*16 + g*4 + j][q = fr]
    }

    // ---- P = exp2(S*C2), cvt_pk to bf16, wave-local LDS exchange ----
    if (fast) {
      #pragma unroll
      for (int f = 0; f < 4; ++f) {
        const float p0 = __builtin_exp2f(sacc[f][0] * C2);
        const float p1 = __builtin_exp2f(sacc[f][1] * C2);
        const float p2 = __builtin_exp2f(sacc[f][2] * C2);
        const float p3 = __builtin_exp2f(sacc[f][3] * C2);
        u32 lo, hi;
        asm("v_cvt_pk_bf16_f32 %0, %1, %2" : "=v"(lo) : "v"(p0), "v"(p1));
        asm("v_cvt_pk_bf16_f32 %0, %1, %2" : "=v"(hi) : "v"(p2), "v"(p3));
        const int sel = (4 * f + g) ^ c3;
        *reinterpret_cast<uint2*>(&pw[fr * 36 + sel * 2]) = make_uint2(lo, hi);
      }
    } else {
      #pragma unroll
      for (int f = 0; f < 4; ++f) {
        float pj[4];
        #pragma unroll
        for (int j = 0; j < 4; ++j) {
          const int kk = f * 16 + g * 4 + j;
          float e = sacc[f][j] * C2;
          if (qsgl != ksegs[cur][kk]) e = -1e30f;  // exp2(-inf) = 0
          pj[j] = __builtin_exp2f(e);
        }
        u32 lo, hi;
        asm("v_cvt_pk_bf16_f32 %0, %1, %2" : "=v"(lo) : "v"(pj[0]), "v"(pj[1]));
        asm("v_cvt_pk_bf16_f32 %0, %1, %2" : "=v"(hi) : "v"(pj[2]), "v"(pj[3]));
        const int sel = (4 * f + g) ^ c3;
        *reinterpret_cast<uint2*>(&pw[fr * 36 + sel * 2]) = make_uint2(lo, hi);
      }
    }
    // cross-lane LDS dep within the wave: drain DS writes, pin reads after
    asm volatile("s_waitcnt lgkmcnt(0)" ::: "memory");
    __builtin_amdgcn_sched_barrier(0);
    bf16x8 pa0 = *reinterpret_cast<const bf16x8*>(&pw[fr * 36 + ((sA ^ c3) * 2)]);
    bf16x8 pa1 = *reinterpret_cast<const bf16x8*>(&pw[fr * 36 + (((8 + sA) ^ c3) * 2)]);

    // ---- PV (+ ones-row l-sum in dt=5), swizzled V reads ----
    const u16* vb = V_lds[cur];
    #pragma unroll
    for (int dt = 0; dt < 6; ++dt) {
      const int row = dt * 16 + fr;
      const u16* vp = vb + row * 64;
      bf16x8 vb0 = *reinterpret_cast<const bf16x8*>(vp + ((g ^ (fr & 7)) * 8));
      bf16x8 vb1 = *reinterpret_cast<const bf16x8*>(vp + ((((4 + g)) ^ (fr & 7)) * 8));
      acc[dt] = __builtin_amdgcn_mfma_f32_16x16x32_bf16(pa0, vb0, acc[dt], 0, 0, 0);
      acc[dt] = __builtin_amdgcn_mfma_f32_16x16x32_bf16(pa1, vb1, acc[dt], 0, 0, 0);
    }

    __syncthreads();
  }
  #undef ASTAGE
  #undef SSTAGE

  // ---- epilogue (acc[dt][j] = O[q-row g*4+j][d=dt*16+fr]) ----
  #pragma unroll
  for (int j = 0; j < 4; ++j) {
    const float lsum = __shfl(acc[5][j], l & 48);  // lane (g, fr=0): ones-row sum
    const float il = (lsum > 0.f) ? 1.0f / lsum : 0.f;
    const int row = t0 + w * 16 + g * 4 + j;
    #pragma unroll
    for (int dt = 0; dt < 5; ++dt)
      attn_bf[(size_t)row * EMB + h * HD + dt * 16 + fr] = f2bf(acc[dt][j] * il);
  }
}

extern "C" void kernel_launch(void* const* d_in, const int* in_sizes, int n_in,
                              void* d_out, int out_size, void* d_ws, size_t ws_size,
                              hipStream_t stream) {
  const float* hidden = (const float*)d_in[0];
  const int*   cu     = (const int*)d_in[1];
  const float* rope   = (const float*)d_in[2];
  const float* w_qkv  = (const float*)d_in[3];
  const float* w_o    = (const float*)d_in[4];
  const float* qw     = (const float*)d_in[5];
  const float* kw     = (const float*)d_in[6];
  float* out = (float*)d_out;

  const int T = in_sizes[0] / EMB;   // 4096
  const int n_seq = in_sizes[1] - 1; // 8

  // workspace (~37MB): qkv_bf | hid_bf(=attn_bf alias) | wqkv_bf | wo_bf | v_t | seg
  u16* qkv_bf  = (u16*)d_ws;
  u16* hid_bf  = qkv_bf + (size_t)T * QKV_ROW;
  u16* attn_bf = hid_bf;  // alias: hid_bf dead after gemm_qkv
  u16* wqkv_bf = hid_bf + (size_t)T * EMB;
  u16* wo_bf   = wqkv_bf + (size_t)QKV_ROW * EMB;
  u16* v_t     = wo_bf + (size_t)EMB * EMB;           // [320][4096] + slack
  int* segb    = (int*)(v_t + (size_t)320 * 4096 + 64);

  const int nq_hid = T * EMB / 4, nq_wqkv = QKV_ROW * EMB / 4, nq_wo = EMB * EMB / 4;
  const int nq_tot = nq_hid + nq_wqkv + nq_wo;
  prep_kernel<<<(nq_tot + 255) / 256, 256, 0, stream>>>(
      hidden, w_qkv, w_o, cu, n_seq, T, hid_bf, wqkv_bf, wo_bf, segb,
      nq_hid, nq_wqkv, nq_wo);

  // qkv[:,0:1600] + v_t = hidden @ w_qkv^T  (V columns transposed; grid 480 % 8 == 0)
  {
    const int gx = 15, nwg = gx * (T / 128);  // 480
    gemm_bf16<u16, true><<<nwg, 256, 0, stream>>>(hid_bf, wqkv_bf, qkv_bf, v_t,
                                                  T, QKV_ROW, EMB, QKV_ROW, gx, nwg);
  }
  norm_rope_bf<<<T, 320, 0, stream>>>(qkv_bf, rope, qw, kw);
  attn_v7<<<dim3(T / QT, H_Q), 512, 0, stream>>>(qkv_bf, v_t, segb, cu, T, attn_bf);
  // out = attn @ w_o^T  (fp32 out; grid 320 % 8 == 0)
  {
    const int gx = 10, nwg = gx * (T / 128);  // 320
    gemm_bf16<float, false><<<nwg, 256, 0, stream>>>(attn_bf, wo_bf, out, nullptr,
                                                     T, EMB, EMB, EMB, gx, nwg);
  }
}

// Round 13
// 121.299 us; speedup vs baseline: 1.1012x; 1.0210x over previous
//
#include <hip/hip_runtime.h>
#include <hip/hip_bf16.h>

#define H_Q 16
#define H_KV 4
#define HD 80
#define QKV_ROW 1920   // qkv buffer row stride (cols 0..1599 live: Q,K)
#define K_OFF 1280     // 16*80
#define EMB 1280
#define QT 128         // query tile rows (8 waves)
#define KC 64          // k/v chunk rows
#define KROW 80        // K_lds row stride (u16), unpadded
#define VTS 4096       // v_t row stride (tokens)

typedef unsigned short u16;
typedef unsigned int u32;
typedef __attribute__((ext_vector_type(8))) short bf16x8;
typedef __attribute__((ext_vector_type(4))) float f32x4;

__device__ inline u16 f2bf(float f) {
  unsigned u = __float_as_uint(f);
  unsigned r = (u + 0x7FFFu + ((u >> 16) & 1u)) >> 16;
  return (u16)r;
}
__device__ inline float bf2f(u16 v) { return __uint_as_float(((unsigned)v) << 16); }

__device__ inline void cvt4(const float* __restrict__ in, u16* __restrict__ out, int q) {
  float4 v = *reinterpret_cast<const float4*>(in + q * 4);
  ushort4 o;
  o.x = f2bf(v.x); o.y = f2bf(v.y); o.z = f2bf(v.z); o.w = f2bf(v.w);
  *reinterpret_cast<ushort4*>(out + q * 4) = o;
}

// ---------------- fused prep: 3x fp32->bf16 + seg ids ----------------
__global__ __launch_bounds__(256) void prep_kernel(const float* __restrict__ hidden,
                                                   const float* __restrict__ w_qkv,
                                                   const float* __restrict__ w_o,
                                                   const int* __restrict__ cu, int n_seq, int T,
                                                   u16* __restrict__ hid_bf,
                                                   u16* __restrict__ wqkv_bf,
                                                   u16* __restrict__ wo_bf,
                                                   int* __restrict__ seg,
                                                   int nq_hid, int nq_wqkv, int nq_wo) {
  const int i = blockIdx.x * 256 + threadIdx.x;
  if (i < T) {
    int s = 0;
    for (int k = 1; k <= n_seq; ++k) s += (i >= cu[k]) ? 1 : 0;
    seg[i] = s;
  }
  int q = i;
  if (q < nq_hid) { cvt4(hidden, hid_bf, q); return; }
  q -= nq_hid;
  if (q < nq_wqkv) { cvt4(w_qkv, wqkv_bf, q); return; }
  q -= nq_wqkv;
  if (q < nq_wo) cvt4(w_o, wo_bf, q);
}

// ---------------- bf16 MFMA GEMM: C[M,N] = A[M,K] * B[N,K]^T ----------------
// 128x64 tile (latency-bound fix: 2x blocks vs 128x128 -> ~15 waves/CU), 4 waves
// as 2Mx2N (wave tile 64x32), 16x16x32 MFMA. 3 LDS buffers, prefetch distance 2,
// counted vmcnt (3 vmem/stage -> 6/3/0). Bank-clean ds_read pattern (fr rows, fq*16B).
// VSPLIT: column-fragments with col>=1600 are written TRANSPOSED to vt[col-1600][row].
template <typename OUT, bool VSPLIT>
__global__ __launch_bounds__(256) void gemm_bf16(const u16* __restrict__ A,
                                                 const u16* __restrict__ B,
                                                 OUT* __restrict__ C,
                                                 u16* __restrict__ vt,
                                                 int M, int N, int K, int ldc,
                                                 int gx, int nwg) {
  __shared__ u16 As[3][128 * 32];
  __shared__ u16 Bs[3][64 * 32];
  const int tid = threadIdx.x;
  const int id = blockIdx.x;
  const int sw = (id & 7) * (nwg >> 3) + (id >> 3);  // nwg % 8 == 0 guaranteed
  const int bm = (sw / gx) * 128;
  const int bn = (sw % gx) * 64;
  const int w = tid >> 6;
  const int l = tid & 63;
  const int wr = (w >> 1) * 64, wc = (w & 1) * 32;
  const int fr = l & 15;
  const int fq = l >> 4;
  const int arow = tid >> 2, acol = (tid & 3) * 8;

  f32x4 acc[4][2];
  #pragma unroll
  for (int mi = 0; mi < 4; ++mi)
    #pragma unroll
    for (int ni = 0; ni < 2; ++ni) acc[mi][ni] = (f32x4){0.f, 0.f, 0.f, 0.f};

  // 3 global_load_lds (vmem ops) per thread per STAGE (2 for A, 1 for B)
  #define GSTAGE(buf, k0)                                                             \
    do {                                                                              \
      _Pragma("unroll")                                                               \
      for (int it = 0; it < 2; ++it) {                                                \
        const u16* ga = A + (size_t)(bm + it * 64 + arow) * K + (k0) + acol;          \
        __builtin_amdgcn_global_load_lds(                                             \
            (const __attribute__((address_space(1))) unsigned int*)ga,                \
            (__attribute__((address_space(3))) unsigned int*)&As[buf][it * 2048 + tid * 8], 16, 0, 0); \
      }                                                                               \
      const u16* gb = B + (size_t)(bn + arow) * K + (k0) + acol;                      \
      __builtin_amdgcn_global_load_lds(                                               \
          (const __attribute__((address_space(1))) unsigned int*)gb,                  \
          (__attribute__((address_space(3))) unsigned int*)&Bs[buf][tid * 8], 16, 0, 0); \
    } while (0)

  const int nt = K >> 5;  // >= 2 for all our shapes (K=1280 -> 40)
  GSTAGE(0, 0);
  GSTAGE(1, 32);

  int cur = 0;
  for (int t = 0; t < nt; ++t) {
    if (t + 2 < nt) {
      const int nb = (cur + 2) % 3;
      GSTAGE(nb, (t + 2) * 32);
      asm volatile("s_waitcnt vmcnt(6)" ::: "memory");   // stages t+1,t+2 in flight
    } else if (t + 1 < nt) {
      asm volatile("s_waitcnt vmcnt(3)" ::: "memory");
    } else {
      asm volatile("s_waitcnt vmcnt(0)" ::: "memory");
    }
    __builtin_amdgcn_s_barrier();           // all waves: buf[cur] DMA complete
    __builtin_amdgcn_sched_barrier(0);      // pin ds_reads after the wait

    bf16x8 af[4], bfr[2];
    #pragma unroll
    for (int mi = 0; mi < 4; ++mi)
      af[mi] = *reinterpret_cast<const bf16x8*>(&As[cur][(wr + mi * 16 + fr) * 32 + fq * 8]);
    #pragma unroll
    for (int ni = 0; ni < 2; ++ni)
      bfr[ni] = *reinterpret_cast<const bf16x8*>(&Bs[cur][(wc + ni * 16 + fr) * 32 + fq * 8]);
    __builtin_amdgcn_s_setprio(1);
    #pragma unroll
    for (int mi = 0; mi < 4; ++mi)
      #pragma unroll
      for (int ni = 0; ni < 2; ++ni)
        acc[mi][ni] = __builtin_amdgcn_mfma_f32_16x16x32_bf16(af[mi], bfr[ni], acc[mi][ni], 0, 0, 0);
    __builtin_amdgcn_s_setprio(0);

    __builtin_amdgcn_sched_barrier(0);
    __builtin_amdgcn_s_barrier();           // all waves' reads of buf[cur] done
    cur = (cur + 1) % 3;
  }
  #undef GSTAGE

  #pragma unroll
  for (int mi = 0; mi < 4; ++mi)
    #pragma unroll
    for (int ni = 0; ni < 2; ++ni) {
      const int col = bn + wc + ni * 16 + fr;
      const int row0 = bm + wr + mi * 16 + fq * 4;
      if (VSPLIT && col >= 1600) {
        // transposed V write: vt[col-1600][row0..row0+3] (8B packed store)
        ushort4 o;
        o.x = f2bf(acc[mi][ni][0]); o.y = f2bf(acc[mi][ni][1]);
        o.z = f2bf(acc[mi][ni][2]); o.w = f2bf(acc[mi][ni][3]);
        *reinterpret_cast<ushort4*>(&vt[(size_t)(col - 1600) * VTS + row0]) = o;
      } else {
        #pragma unroll
        for (int j = 0; j < 4; ++j) {
          if constexpr (sizeof(OUT) == 2)
            C[(size_t)(row0 + j) * ldc + col] = f2bf(acc[mi][ni][j]);
          else
            C[(size_t)(row0 + j) * ldc + col] = acc[mi][ni][j];
        }
      }
    }
}

// ---------------- per-token RMSNorm + RoPE ----------------
// grid = T, block 320 (5 waves); wave w handles heads w*4 .. w*4+3.
// NOTE: the rotate-half read xs[w][d +/- 40] is a CROSS-LANE dependency through
// LDS; __syncthreads() between write and read is REQUIRED (R6/R7 failure).
__global__ __launch_bounds__(320) void norm_rope_bf(u16* __restrict__ qkv,
                                                    const float* __restrict__ freqs,
                                                    const float* __restrict__ qw,
                                                    const float* __restrict__ kw) {
  const int t = blockIdx.x;
  const int tid = threadIdx.x;
  __shared__ float cs[HD], sn[HD];
  __shared__ float wq[HD], wk[HD];
  __shared__ float xs[5][HD];
  if (tid < HD) {
    const float f = freqs[(size_t)t * HD + tid];
    cs[tid] = __cosf(f);
    sn[tid] = __sinf(f);
    wq[tid] = qw[tid];
    wk[tid] = kw[tid];
  }
  __syncthreads();
  const int w = tid >> 6, lane = tid & 63;
  #pragma unroll
  for (int i = 0; i < 4; ++i) {
    const int hh = w * 4 + i;
    const bool is_q = (hh < H_Q);
    u16* x = qkv + (size_t)t * QKV_ROW + (is_q ? hh * HD : K_OFF + (hh - H_Q) * HD);
    const float* wt = is_q ? wq : wk;
    float a = bf2f(x[lane]);
    float b = (lane < HD - 64) ? bf2f(x[64 + lane]) : 0.0f;
    float ss = a * a + b * b;
    #pragma unroll
    for (int off = 32; off; off >>= 1) ss += __shfl_down(ss, off);
    ss = __shfl(ss, 0);
    const float inv = rsqrtf(ss * (1.0f / HD) + 1e-6f);
    xs[w][lane] = a * inv * wt[lane];
    if (lane < HD - 64) xs[w][64 + lane] = b * inv * wt[64 + lane];
    __syncthreads();  // REQUIRED: cross-lane LDS dep
    {
      const int d = lane;
      const float rot = (d < HD / 2) ? -xs[w][d + HD / 2] : xs[w][d - HD / 2];
      x[d] = f2bf(xs[w][d] * cs[d] + rot * sn[d]);
    }
    if (lane < HD - 64) {
      const int d = 64 + lane;
      const float rot = (d < HD / 2) ? -xs[w][d + HD / 2] : xs[w][d - HD / 2];
      x[d] = f2bf(xs[w][d] * cs[d] + rot * sn[d]);
    }
    __syncthreads();  // all reads done before next iteration's writes
  }
}

// ---------------- MFMA flash attention v7 (R10-verified) ----------------
// grid (T/QT, 16), 8 waves. Swapped QK^T (S^T = mfma(K, Q)): lane (g,fr) holds
// P[k=f*16+g*4+j][q=fr] -> P stays in registers; cvt_pk to bf16 and a per-wave
// LDS exchange (4x ds_write_b64 + 2x ds_read_b128, XOR-swizzled pairs) builds
// PV's A-fragments pa0=P[fr][8g..8g+7], pa1=P[fr][32+8g..+7].
// No online max (RMSNorm bounds |S*scale| <= ~9.0 -> exp2 <= 8.2e3, finite).
// l-sum free via ones-row MFMA.
__global__ __launch_bounds__(512) void attn_v7(const u16* __restrict__ qkv,
                                               const u16* __restrict__ vt,
                                               const int* __restrict__ seg,
                                               const int* __restrict__ cu,
                                               int T,
                                               u16* __restrict__ attn_bf) {
  __shared__ u16 K_lds[2][KC * KROW + 16];  // +16 slack (zeroed) for g=3 overread on row 63
  __shared__ u16 V_lds[2][96 * 64];         // V^T rows 0..79 staged; 80=ones, 81..95=0
  __shared__ u32 Pw[8][16 * 36];            // per-wave P exchange: fr stride 36 u32
  __shared__ int ksegs[2][KC];

  const int t0 = blockIdx.x * QT;
  const int h = blockIdx.y;
  const int kvh = h >> 2;
  const int tid = threadIdx.x;
  const int w = tid >> 6, l = tid & 63;
  const int g = l >> 4, fr = l & 15;

  for (int i = tid; i < 2 * 16 * 32; i += 512) {
    const int b = i >> 9, r = (i >> 5) & 15, c = i & 31;
    ((u32*)V_lds[b])[(80 + r) * 32 + c] = (r == 0) ? 0x3f803f80u : 0u;
  }
  if (tid < 16) { K_lds[0][KC * KROW + tid] = 0; K_lds[1][KC * KROW + tid] = 0; }

  const int s0_ = seg[t0], s1_ = seg[t0 + QT - 1];
  const int kbeg = cu[s0_], kend = cu[s1_ + 1];
  const bool fast = (s0_ == s1_) && (((kend - kbeg) & (KC - 1)) == 0) && ((kbeg & 7) == 0);

  // Q fragments (registers). head-dim padded 80->96 with zeros.
  const int qrow = t0 + w * 16 + fr;
  const u16* qp = qkv + (size_t)qrow * QKV_ROW + h * HD;
  bf16x8 qa0 = *reinterpret_cast<const bf16x8*>(qp + g * 8);
  bf16x8 qa1 = *reinterpret_cast<const bf16x8*>(qp + 32 + g * 8);
  bf16x8 qa2 = (g < 2) ? *reinterpret_cast<const bf16x8*>(qp + 64 + g * 8)
                       : (bf16x8)(short)0;
  const int qsgl = seg[qrow];  // swapped layout: lane's q-row is fr-based

  f32x4 acc[6];
  #pragma unroll
  for (int dt = 0; dt < 6; ++dt) acc[dt] = (f32x4){0.f, 0.f, 0.f, 0.f};
  const float C2 = 0.16130010464f;  // (1/sqrt(80)) * log2(e)

  #define ASTAGE(nb, cc)                                                               \
    do {                                                                               \
      for (int i = tid; i < 640; i += 512) {                                           \
        const int kr = i / 10, kc_ = i - kr * 10;                                      \
        const u16* gk = qkv + (size_t)((cc) + kr) * QKV_ROW + K_OFF + kvh * HD + kc_ * 8; \
        __builtin_amdgcn_global_load_lds(                                              \
            (const __attribute__((address_space(1))) u32*)gk,                          \
            (__attribute__((address_space(3))) u32*)&K_lds[nb][i * 8], 16, 0, 0);      \
        const int vr = i >> 3, vs = i & 7;                                             \
        const u16* gv = vt + (size_t)(kvh * HD + vr) * VTS + (cc) + ((vs ^ (vr & 7)) * 8); \
        __builtin_amdgcn_global_load_lds(                                              \
            (const __attribute__((address_space(1))) u32*)gv,                          \
            (__attribute__((address_space(3))) u32*)&V_lds[nb][i * 8], 16, 0, 0);      \
      }                                                                                \
    } while (0)

  #define SSTAGE(nb, cc)                                                               \
    do {                                                                               \
      for (int i = tid; i < KC * 40; i += 512) {                                       \
        const int r = i / 40, ccc = i - r * 40;                                        \
        u32 v = 0;                                                                     \
        if ((cc) + r < kend)                                                           \
          v = reinterpret_cast<const u32*>(qkv + (size_t)((cc) + r) * QKV_ROW + K_OFF + kvh * HD)[ccc]; \
        ((u32*)K_lds[nb])[i] = v;                                                      \
      }                                                                                \
      for (int i = tid; i < HD * KC; i += 512) {                                       \
        const int vr = i >> 6, k = i & 63;                                             \
        u16 v = 0;                                                                     \
        if ((cc) + k < kend)                                                           \
          v = vt[(size_t)(kvh * HD + vr) * VTS + (cc) + k];                            \
        V_lds[nb][vr * 64 + (((k >> 3) ^ (vr & 7)) * 8) + (k & 7)] = v;                \
      }                                                                                \
      if (tid < KC) ksegs[nb][tid] = ((cc) + tid < kend) ? seg[(cc) + tid] : -1;       \
    } while (0)

  if (fast) ASTAGE(0, kbeg); else SSTAGE(0, kbeg);
  __syncthreads();

  const int c3 = (fr & 3) << 2;       // pair-granularity XOR swizzle key
  u32* pw = &Pw[w][0];
  const int sA = 4 * (g >> 1) + 2 * (g & 1);

  int nb = 0;
  for (int c = kbeg; c < kend; c += KC) {
    const int cur = nb;
    nb ^= 1;
    if (c + KC < kend) {
      if (fast) ASTAGE(nb, c + KC); else SSTAGE(nb, c + KC);
    }

    // ---- S^T = K Q^T (swapped operands) ----
    const u16* kb = K_lds[cur];
    f32x4 sacc[4];
    #pragma unroll
    for (int f = 0; f < 4; ++f) {
      const u16* kp = kb + (f * 16 + fr) * KROW;
      bf16x8 b0 = *reinterpret_cast<const bf16x8*>(kp + g * 8);
      bf16x8 b1 = *reinterpret_cast<const bf16x8*>(kp + 32 + g * 8);
      bf16x8 b2 = *reinterpret_cast<const bf16x8*>(kp + 64 + g * 8);
      f32x4 s = (f32x4){0.f, 0.f, 0.f, 0.f};
      s = __builtin_amdgcn_mfma_f32_16x16x32_bf16(b0, qa0, s, 0, 0, 0);
      s = __builtin_amdgcn_mfma_f32_16x16x32_bf16(b1, qa1, s, 0, 0, 0);
      s = __builtin_amdgcn_mfma_f32_16x16x32_bf16(b2, qa2, s, 0, 0, 0);
      sacc[f] = s;  // sacc[f][j] = S[k = c + f*16 + g*4 + j][q = fr]
    }

    // ---- P = exp2(S*C2), cvt_pk to bf16, wave-local LDS exchange ----
    if (fast) {
      #pragma unroll
      for (int f = 0; f < 4; ++f) {
        const float p0 = __builtin_exp2f(sacc[f][0] * C2);
        const float p1 = __builtin_exp2f(sacc[f][1] * C2);
        const float p2 = __builtin_exp2f(sacc[f][2] * C2);
        const float p3 = __builtin_exp2f(sacc[f][3] * C2);
        u32 lo, hi;
        asm("v_cvt_pk_bf16_f32 %0, %1, %2" : "=v"(lo) : "v"(p0), "v"(p1));
        asm("v_cvt_pk_bf16_f32 %0, %1, %2" : "=v"(hi) : "v"(p2), "v"(p3));
        const int sel = (4 * f + g) ^ c3;
        *reinterpret_cast<uint2*>(&pw[fr * 36 + sel * 2]) = make_uint2(lo, hi);
      }
    } else {
      #pragma unroll
      for (int f = 0; f < 4; ++f) {
        float pj[4];
        #pragma unroll
        for (int j = 0; j < 4; ++j) {
          const int kk = f * 16 + g * 4 + j;
          float e = sacc[f][j] * C2;
          if (qsgl != ksegs[cur][kk]) e = -1e30f;  // exp2(-inf) = 0
          pj[j] = __builtin_exp2f(e);
        }
        u32 lo, hi;
        asm("v_cvt_pk_bf16_f32 %0, %1, %2" : "=v"(lo) : "v"(pj[0]), "v"(pj[1]));
        asm("v_cvt_pk_bf16_f32 %0, %1, %2" : "=v"(hi) : "v"(pj[2]), "v"(pj[3]));
        const int sel = (4 * f + g) ^ c3;
        *reinterpret_cast<uint2*>(&pw[fr * 36 + sel * 2]) = make_uint2(lo, hi);
      }
    }
    // cross-lane LDS dep within the wave: drain DS writes, pin reads after
    asm volatile("s_waitcnt lgkmcnt(0)" ::: "memory");
    __builtin_amdgcn_sched_barrier(0);
    bf16x8 pa0 = *reinterpret_cast<const bf16x8*>(&pw[fr * 36 + ((sA ^ c3) * 2)]);
    bf16x8 pa1 = *reinterpret_cast<const bf16x8*>(&pw[fr * 36 + (((8 + sA) ^ c3) * 2)]);

    // ---- PV (+ ones-row l-sum in dt=5), swizzled V reads ----
    const u16* vb = V_lds[cur];
    #pragma unroll
    for (int dt = 0; dt < 6; ++dt) {
      const int row = dt * 16 + fr;
      const u16* vp = vb + row * 64;
      bf16x8 vb0 = *reinterpret_cast<const bf16x8*>(vp + ((g ^ (fr & 7)) * 8));
      bf16x8 vb1 = *reinterpret_cast<const bf16x8*>(vp + ((((4 + g)) ^ (fr & 7)) * 8));
      acc[dt] = __builtin_amdgcn_mfma_f32_16x16x32_bf16(pa0, vb0, acc[dt], 0, 0, 0);
      acc[dt] = __builtin_amdgcn_mfma_f32_16x16x32_bf16(pa1, vb1, acc[dt], 0, 0, 0);
    }

    __syncthreads();
  }
  #undef ASTAGE
  #undef SSTAGE

  // ---- epilogue (acc[dt][j] = O[q-row g*4+j][d=dt*16+fr]) ----
  #pragma unroll
  for (int j = 0; j < 4; ++j) {
    const float lsum = __shfl(acc[5][j], l & 48);  // lane (g, fr=0): ones-row sum
    const float il = (lsum > 0.f) ? 1.0f / lsum : 0.f;
    const int row = t0 + w * 16 + g * 4 + j;
    #pragma unroll
    for (int dt = 0; dt < 5; ++dt)
      attn_bf[(size_t)row * EMB + h * HD + dt * 16 + fr] = f2bf(acc[dt][j] * il);
  }
}

extern "C" void kernel_launch(void* const* d_in, const int* in_sizes, int n_in,
                              void* d_out, int out_size, void* d_ws, size_t ws_size,
                              hipStream_t stream) {
  const float* hidden = (const float*)d_in[0];
  const int*   cu     = (const int*)d_in[1];
  const float* rope   = (const float*)d_in[2];
  const float* w_qkv  = (const float*)d_in[3];
  const float* w_o    = (const float*)d_in[4];
  const float* qw     = (const float*)d_in[5];
  const float* kw     = (const float*)d_in[6];
  float* out = (float*)d_out;

  const int T = in_sizes[0] / EMB;   // 4096
  const int n_seq = in_sizes[1] - 1; // 8

  // workspace (~37MB): qkv_bf | hid_bf(=attn_bf alias) | wqkv_bf | wo_bf | v_t | seg
  u16* qkv_bf  = (u16*)d_ws;
  u16* hid_bf  = qkv_bf + (size_t)T * QKV_ROW;
  u16* attn_bf = hid_bf;  // alias: hid_bf dead after gemm_qkv
  u16* wqkv_bf = hid_bf + (size_t)T * EMB;
  u16* wo_bf   = wqkv_bf + (size_t)QKV_ROW * EMB;
  u16* v_t     = wo_bf + (size_t)EMB * EMB;           // [320][4096] + slack
  int* segb    = (int*)(v_t + (size_t)320 * 4096 + 64);

  const int nq_hid = T * EMB / 4, nq_wqkv = QKV_ROW * EMB / 4, nq_wo = EMB * EMB / 4;
  const int nq_tot = nq_hid + nq_wqkv + nq_wo;
  prep_kernel<<<(nq_tot + 255) / 256, 256, 0, stream>>>(
      hidden, w_qkv, w_o, cu, n_seq, T, hid_bf, wqkv_bf, wo_bf, segb,
      nq_hid, nq_wqkv, nq_wo);

  // qkv[:,0:1600] + v_t = hidden @ w_qkv^T  (V columns transposed; grid 960 % 8 == 0)
  {
    const int gx = QKV_ROW / 64, nwg = gx * (T / 128);  // 30 * 32 = 960
    gemm_bf16<u16, true><<<nwg, 256, 0, stream>>>(hid_bf, wqkv_bf, qkv_bf, v_t,
                                                  T, QKV_ROW, EMB, QKV_ROW, gx, nwg);
  }
  norm_rope_bf<<<T, 320, 0, stream>>>(qkv_bf, rope, qw, kw);
  attn_v7<<<dim3(T / QT, H_Q), 512, 0, stream>>>(qkv_bf, v_t, segb, cu, T, attn_bf);
  // out = attn @ w_o^T  (fp32 out; grid 640 % 8 == 0)
  {
    const int gx = EMB / 64, nwg = gx * (T / 128);  // 20 * 32 = 640
    gemm_bf16<float, false><<<nwg, 256, 0, stream>>>(attn_bf, wo_bf, out, nullptr,
                                                     T, EMB, EMB, EMB, gx, nwg);
  }
}

// Round 14
// 115.103 us; speedup vs baseline: 1.1605x; 1.0538x over previous
//
#include <hip/hip_runtime.h>
#include <hip/hip_bf16.h>

#define H_Q 16
#define H_KV 4
#define HD 80
#define QKV_ROW 1920   // qkv buffer row stride (cols 0..1599 live: Q,K)
#define K_OFF 1280     // 16*80
#define EMB 1280
#define QT 128         // query tile rows (8 waves)
#define KC 64          // k/v chunk rows
#define KROW 80        // K_lds row stride (u16), unpadded
#define VTS 4096       // v_t row stride (tokens)

typedef unsigned short u16;
typedef unsigned int u32;
typedef __attribute__((ext_vector_type(8))) short bf16x8;
typedef __attribute__((ext_vector_type(4))) float f32x4;

__device__ inline u16 f2bf(float f) {
  unsigned u = __float_as_uint(f);
  unsigned r = (u + 0x7FFFu + ((u >> 16) & 1u)) >> 16;
  return (u16)r;
}
__device__ inline float bf2f(u16 v) { return __uint_as_float(((unsigned)v) << 16); }

__device__ inline void cvt4(const float* __restrict__ in, u16* __restrict__ out, int q) {
  float4 v = *reinterpret_cast<const float4*>(in + q * 4);
  ushort4 o;
  o.x = f2bf(v.x); o.y = f2bf(v.y); o.z = f2bf(v.z); o.w = f2bf(v.w);
  *reinterpret_cast<ushort4*>(out + q * 4) = o;
}

// ---------------- fused prep: 3x fp32->bf16 + seg ids ----------------
__global__ __launch_bounds__(256) void prep_kernel(const float* __restrict__ hidden,
                                                   const float* __restrict__ w_qkv,
                                                   const float* __restrict__ w_o,
                                                   const int* __restrict__ cu, int n_seq, int T,
                                                   u16* __restrict__ hid_bf,
                                                   u16* __restrict__ wqkv_bf,
                                                   u16* __restrict__ wo_bf,
                                                   int* __restrict__ seg,
                                                   int nq_hid, int nq_wqkv, int nq_wo) {
  const int i = blockIdx.x * 256 + threadIdx.x;
  if (i < T) {
    int s = 0;
    for (int k = 1; k <= n_seq; ++k) s += (i >= cu[k]) ? 1 : 0;
    seg[i] = s;
  }
  int q = i;
  if (q < nq_hid) { cvt4(hidden, hid_bf, q); return; }
  q -= nq_hid;
  if (q < nq_wqkv) { cvt4(w_qkv, wqkv_bf, q); return; }
  q -= nq_wqkv;
  if (q < nq_wo) cvt4(w_o, wo_bf, q);
}

// ---------------- bf16 MFMA GEMM: C[M,N] = A[M,K] * B[N,K]^T ----------------
// 128x64 tile, BK=64 (16 MFMA + 12 ds_read per barrier-pair; 20 iters at K=1280 —
// halves barrier crossings vs BK=32). 2 LDS buffers (48KB -> 3 blocks/CU), prefetch
// distance 1, counted vmcnt(6). 8-slot XOR swizzle (phys = log ^ (row&7)): source
// col pre-swizzled, LDS dest linear (T21), reads apply same XOR -> 2 lanes/bank.
// VSPLIT: column-fragments with col>=1600 are written TRANSPOSED to vt[col-1600][row].
template <typename OUT, bool VSPLIT>
__global__ __launch_bounds__(256) void gemm_bf16(const u16* __restrict__ A,
                                                 const u16* __restrict__ B,
                                                 OUT* __restrict__ C,
                                                 u16* __restrict__ vt,
                                                 int M, int N, int K, int ldc,
                                                 int gx, int nwg) {
  __shared__ u16 As[2][128 * 64];
  __shared__ u16 Bs[2][64 * 64];
  const int tid = threadIdx.x;
  const int id = blockIdx.x;
  const int sw = (id & 7) * (nwg >> 3) + (id >> 3);  // nwg % 8 == 0 guaranteed
  const int bm = (sw / gx) * 128;
  const int bn = (sw % gx) * 64;
  const int w = tid >> 6;
  const int l = tid & 63;
  const int wr = (w >> 1) * 64, wc = (w & 1) * 32;
  const int fr = l & 15;
  const int fq = l >> 4;
  const int srow = tid >> 3;                              // staging row within 32-row group
  const int scol = ((tid & 7) ^ ((tid >> 3) & 7)) * 8;    // pre-swizzled source k-slot

  f32x4 acc[4][2];
  #pragma unroll
  for (int mi = 0; mi < 4; ++mi)
    #pragma unroll
    for (int ni = 0; ni < 2; ++ni) acc[mi][ni] = (f32x4){0.f, 0.f, 0.f, 0.f};

  // 6 global_load_lds per STAGE (4 for A 128x64, 2 for B 64x64); dest linear tid*16B
  #define GSTAGE(buf, k0)                                                             \
    do {                                                                              \
      _Pragma("unroll")                                                               \
      for (int it = 0; it < 4; ++it) {                                                \
        const u16* ga = A + (size_t)(bm + it * 32 + srow) * K + (k0) + scol;          \
        __builtin_amdgcn_global_load_lds(                                             \
            (const __attribute__((address_space(1))) unsigned int*)ga,                \
            (__attribute__((address_space(3))) unsigned int*)&As[buf][it * 2048 + tid * 8], 16, 0, 0); \
      }                                                                               \
      _Pragma("unroll")                                                               \
      for (int it = 0; it < 2; ++it) {                                                \
        const u16* gb = B + (size_t)(bn + it * 32 + srow) * K + (k0) + scol;          \
        __builtin_amdgcn_global_load_lds(                                             \
            (const __attribute__((address_space(1))) unsigned int*)gb,                \
            (__attribute__((address_space(3))) unsigned int*)&Bs[buf][it * 2048 + tid * 8], 16, 0, 0); \
      }                                                                               \
    } while (0)

  const int nt = K >> 6;  // K=1280 -> 20
  GSTAGE(0, 0);

  for (int t = 0; t < nt; ++t) {
    const int cur = t & 1;
    if (t + 1 < nt) {
      GSTAGE(cur ^ 1, (t + 1) * 64);      // buf read at t-1; protected by t-1's end barrier
      asm volatile("s_waitcnt vmcnt(6)" ::: "memory");   // own stage done, next in flight
    } else {
      asm volatile("s_waitcnt vmcnt(0)" ::: "memory");
    }
    __builtin_amdgcn_s_barrier();           // all waves: buf[cur] DMA complete
    __builtin_amdgcn_sched_barrier(0);      // pin ds_reads after the wait

    bf16x8 af[4][2], bfr[2][2];
    #pragma unroll
    for (int mi = 0; mi < 4; ++mi)
      #pragma unroll
      for (int kk = 0; kk < 2; ++kk) {
        const int ps = ((kk * 4 + fq) ^ (fr & 7)) * 8;   // swizzled physical slot
        af[mi][kk] = *reinterpret_cast<const bf16x8*>(&As[cur][(wr + mi * 16 + fr) * 64 + ps]);
      }
    #pragma unroll
    for (int ni = 0; ni < 2; ++ni)
      #pragma unroll
      for (int kk = 0; kk < 2; ++kk) {
        const int ps = ((kk * 4 + fq) ^ (fr & 7)) * 8;
        bfr[ni][kk] = *reinterpret_cast<const bf16x8*>(&Bs[cur][(wc + ni * 16 + fr) * 64 + ps]);
      }
    __builtin_amdgcn_s_setprio(1);
    #pragma unroll
    for (int kk = 0; kk < 2; ++kk)
      #pragma unroll
      for (int mi = 0; mi < 4; ++mi)
        #pragma unroll
        for (int ni = 0; ni < 2; ++ni)
          acc[mi][ni] = __builtin_amdgcn_mfma_f32_16x16x32_bf16(af[mi][kk], bfr[ni][kk],
                                                               acc[mi][ni], 0, 0, 0);
    __builtin_amdgcn_s_setprio(0);

    __builtin_amdgcn_sched_barrier(0);
    __builtin_amdgcn_s_barrier();           // all waves' reads of buf[cur] done
  }
  #undef GSTAGE

  #pragma unroll
  for (int mi = 0; mi < 4; ++mi)
    #pragma unroll
    for (int ni = 0; ni < 2; ++ni) {
      const int col = bn + wc + ni * 16 + fr;
      const int row0 = bm + wr + mi * 16 + fq * 4;
      if (VSPLIT && col >= 1600) {
        // transposed V write: vt[col-1600][row0..row0+3] (8B packed store)
        ushort4 o;
        o.x = f2bf(acc[mi][ni][0]); o.y = f2bf(acc[mi][ni][1]);
        o.z = f2bf(acc[mi][ni][2]); o.w = f2bf(acc[mi][ni][3]);
        *reinterpret_cast<ushort4*>(&vt[(size_t)(col - 1600) * VTS + row0]) = o;
      } else {
        #pragma unroll
        for (int j = 0; j < 4; ++j) {
          if constexpr (sizeof(OUT) == 2)
            C[(size_t)(row0 + j) * ldc + col] = f2bf(acc[mi][ni][j]);
          else
            C[(size_t)(row0 + j) * ldc + col] = acc[mi][ni][j];
        }
      }
    }
}

// ---------------- per-token RMSNorm + RoPE ----------------
// grid = T, block 320 (5 waves); wave w handles heads w*4 .. w*4+3.
// NOTE: the rotate-half read xs[w][d +/- 40] is a CROSS-LANE dependency through
// LDS; __syncthreads() between write and read is REQUIRED (R6/R7 failure).
__global__ __launch_bounds__(320) void norm_rope_bf(u16* __restrict__ qkv,
                                                    const float* __restrict__ freqs,
                                                    const float* __restrict__ qw,
                                                    const float* __restrict__ kw) {
  const int t = blockIdx.x;
  const int tid = threadIdx.x;
  __shared__ float cs[HD], sn[HD];
  __shared__ float wq[HD], wk[HD];
  __shared__ float xs[5][HD];
  if (tid < HD) {
    const float f = freqs[(size_t)t * HD + tid];
    cs[tid] = __cosf(f);
    sn[tid] = __sinf(f);
    wq[tid] = qw[tid];
    wk[tid] = kw[tid];
  }
  __syncthreads();
  const int w = tid >> 6, lane = tid & 63;
  #pragma unroll
  for (int i = 0; i < 4; ++i) {
    const int hh = w * 4 + i;
    const bool is_q = (hh < H_Q);
    u16* x = qkv + (size_t)t * QKV_ROW + (is_q ? hh * HD : K_OFF + (hh - H_Q) * HD);
    const float* wt = is_q ? wq : wk;
    float a = bf2f(x[lane]);
    float b = (lane < HD - 64) ? bf2f(x[64 + lane]) : 0.0f;
    float ss = a * a + b * b;
    #pragma unroll
    for (int off = 32; off; off >>= 1) ss += __shfl_down(ss, off);
    ss = __shfl(ss, 0);
    const float inv = rsqrtf(ss * (1.0f / HD) + 1e-6f);
    xs[w][lane] = a * inv * wt[lane];
    if (lane < HD - 64) xs[w][64 + lane] = b * inv * wt[64 + lane];
    __syncthreads();  // REQUIRED: cross-lane LDS dep
    {
      const int d = lane;
      const float rot = (d < HD / 2) ? -xs[w][d + HD / 2] : xs[w][d - HD / 2];
      x[d] = f2bf(xs[w][d] * cs[d] + rot * sn[d]);
    }
    if (lane < HD - 64) {
      const int d = 64 + lane;
      const float rot = (d < HD / 2) ? -xs[w][d + HD / 2] : xs[w][d - HD / 2];
      x[d] = f2bf(xs[w][d] * cs[d] + rot * sn[d]);
    }
    __syncthreads();  // all reads done before next iteration's writes
  }
}

// ---------------- MFMA flash attention v7 (R10-verified) ----------------
// grid (T/QT, 16), 8 waves. Swapped QK^T (S^T = mfma(K, Q)): lane (g,fr) holds
// P[k=f*16+g*4+j][q=fr] -> P stays in registers; cvt_pk to bf16 and a per-wave
// LDS exchange (4x ds_write_b64 + 2x ds_read_b128, XOR-swizzled pairs) builds
// PV's A-fragments pa0=P[fr][8g..8g+7], pa1=P[fr][32+8g..+7].
// No online max (RMSNorm bounds |S*scale| <= ~9.0 -> exp2 <= 8.2e3, finite).
// l-sum free via ones-row MFMA.
__global__ __launch_bounds__(512) void attn_v7(const u16* __restrict__ qkv,
                                               const u16* __restrict__ vt,
                                               const int* __restrict__ seg,
                                               const int* __restrict__ cu,
                                               int T,
                                               u16* __restrict__ attn_bf) {
  __shared__ u16 K_lds[2][KC * KROW + 16];  // +16 slack (zeroed) for g=3 overread on row 63
  __shared__ u16 V_lds[2][96 * 64];         // V^T rows 0..79 staged; 80=ones, 81..95=0
  __shared__ u32 Pw[8][16 * 36];            // per-wave P exchange: fr stride 36 u32
  __shared__ int ksegs[2][KC];

  const int t0 = blockIdx.x * QT;
  const int h = blockIdx.y;
  const int kvh = h >> 2;
  const int tid = threadIdx.x;
  const int w = tid >> 6, l = tid & 63;
  const int g = l >> 4, fr = l & 15;

  for (int i = tid; i < 2 * 16 * 32; i += 512) {
    const int b = i >> 9, r = (i >> 5) & 15, c = i & 31;
    ((u32*)V_lds[b])[(80 + r) * 32 + c] = (r == 0) ? 0x3f803f80u : 0u;
  }
  if (tid < 16) { K_lds[0][KC * KROW + tid] = 0; K_lds[1][KC * KROW + tid] = 0; }

  const int s0_ = seg[t0], s1_ = seg[t0 + QT - 1];
  const int kbeg = cu[s0_], kend = cu[s1_ + 1];
  const bool fast = (s0_ == s1_) && (((kend - kbeg) & (KC - 1)) == 0) && ((kbeg & 7) == 0);

  // Q fragments (registers). head-dim padded 80->96 with zeros.
  const int qrow = t0 + w * 16 + fr;
  const u16* qp = qkv + (size_t)qrow * QKV_ROW + h * HD;
  bf16x8 qa0 = *reinterpret_cast<const bf16x8*>(qp + g * 8);
  bf16x8 qa1 = *reinterpret_cast<const bf16x8*>(qp + 32 + g * 8);
  bf16x8 qa2 = (g < 2) ? *reinterpret_cast<const bf16x8*>(qp + 64 + g * 8)
                       : (bf16x8)(short)0;
  const int qsgl = seg[qrow];  // swapped layout: lane's q-row is fr-based

  f32x4 acc[6];
  #pragma unroll
  for (int dt = 0; dt < 6; ++dt) acc[dt] = (f32x4){0.f, 0.f, 0.f, 0.f};
  const float C2 = 0.16130010464f;  // (1/sqrt(80)) * log2(e)

  #define ASTAGE(nb, cc)                                                               \
    do {                                                                               \
      for (int i = tid; i < 640; i += 512) {                                           \
        const int kr = i / 10, kc_ = i - kr * 10;                                      \
        const u16* gk = qkv + (size_t)((cc) + kr) * QKV_ROW + K_OFF + kvh * HD + kc_ * 8; \
        __builtin_amdgcn_global_load_lds(                                              \
            (const __attribute__((address_space(1))) u32*)gk,                          \
            (__attribute__((address_space(3))) u32*)&K_lds[nb][i * 8], 16, 0, 0);      \
        const int vr = i >> 3, vs = i & 7;                                             \
        const u16* gv = vt + (size_t)(kvh * HD + vr) * VTS + (cc) + ((vs ^ (vr & 7)) * 8); \
        __builtin_amdgcn_global_load_lds(                                              \
            (const __attribute__((address_space(1))) u32*)gv,                          \
            (__attribute__((address_space(3))) u32*)&V_lds[nb][i * 8], 16, 0, 0);      \
      }                                                                                \
    } while (0)

  #define SSTAGE(nb, cc)                                                               \
    do {                                                                               \
      for (int i = tid; i < KC * 40; i += 512) {                                       \
        const int r = i / 40, ccc = i - r * 40;                                        \
        u32 v = 0;                                                                     \
        if ((cc) + r < kend)                                                           \
          v = reinterpret_cast<const u32*>(qkv + (size_t)((cc) + r) * QKV_ROW + K_OFF + kvh * HD)[ccc]; \
        ((u32*)K_lds[nb])[i] = v;                                                      \
      }                                                                                \
      for (int i = tid; i < HD * KC; i += 512) {                                       \
        const int vr = i >> 6, k = i & 63;                                             \
        u16 v = 0;                                                                     \
        if ((cc) + k < kend)                                                           \
          v = vt[(size_t)(kvh * HD + vr) * VTS + (cc) + k];                            \
        V_lds[nb][vr * 64 + (((k >> 3) ^ (vr & 7)) * 8) + (k & 7)] = v;                \
      }                                                                                \
      if (tid < KC) ksegs[nb][tid] = ((cc) + tid < kend) ? seg[(cc) + tid] : -1;       \
    } while (0)

  if (fast) ASTAGE(0, kbeg); else SSTAGE(0, kbeg);
  __syncthreads();

  const int c3 = (fr & 3) << 2;       // pair-granularity XOR swizzle key
  u32* pw = &Pw[w][0];
  const int sA = 4 * (g >> 1) + 2 * (g & 1);

  int nb = 0;
  for (int c = kbeg; c < kend; c += KC) {
    const int cur = nb;
    nb ^= 1;
    if (c + KC < kend) {
      if (fast) ASTAGE(nb, c + KC); else SSTAGE(nb, c + KC);
    }

    // ---- S^T = K Q^T (swapped operands) ----
    const u16* kb = K_lds[cur];
    f32x4 sacc[4];
    #pragma unroll
    for (int f = 0; f < 4; ++f) {
      const u16* kp = kb + (f * 16 + fr) * KROW;
      bf16x8 b0 = *reinterpret_cast<const bf16x8*>(kp + g * 8);
      bf16x8 b1 = *reinterpret_cast<const bf16x8*>(kp + 32 + g * 8);
      bf16x8 b2 = *reinterpret_cast<const bf16x8*>(kp + 64 + g * 8);
      f32x4 s = (f32x4){0.f, 0.f, 0.f, 0.f};
      s = __builtin_amdgcn_mfma_f32_16x16x32_bf16(b0, qa0, s, 0, 0, 0);
      s = __builtin_amdgcn_mfma_f32_16x16x32_bf16(b1, qa1, s, 0, 0, 0);
      s = __builtin_amdgcn_mfma_f32_16x16x32_bf16(b2, qa2, s, 0, 0, 0);
      sacc[f] = s;  // sacc[f][j] = S[k = c + f*16 + g*4 + j][q = fr]
    }

    // ---- P = exp2(S*C2), cvt_pk to bf16, wave-local LDS exchange ----
    if (fast) {
      #pragma unroll
      for (int f = 0; f < 4; ++f) {
        const float p0 = __builtin_exp2f(sacc[f][0] * C2);
        const float p1 = __builtin_exp2f(sacc[f][1] * C2);
        const float p2 = __builtin_exp2f(sacc[f][2] * C2);
        const float p3 = __builtin_exp2f(sacc[f][3] * C2);
        u32 lo, hi;
        asm("v_cvt_pk_bf16_f32 %0, %1, %2" : "=v"(lo) : "v"(p0), "v"(p1));
        asm("v_cvt_pk_bf16_f32 %0, %1, %2" : "=v"(hi) : "v"(p2), "v"(p3));
        const int sel = (4 * f + g) ^ c3;
        *reinterpret_cast<uint2*>(&pw[fr * 36 + sel * 2]) = make_uint2(lo, hi);
      }
    } else {
      #pragma unroll
      for (int f = 0; f < 4; ++f) {
        float pj[4];
        #pragma unroll
        for (int j = 0; j < 4; ++j) {
          const int kk = f * 16 + g * 4 + j;
          float e = sacc[f][j] * C2;
          if (qsgl != ksegs[cur][kk]) e = -1e30f;  // exp2(-inf) = 0
          pj[j] = __builtin_exp2f(e);
        }
        u32 lo, hi;
        asm("v_cvt_pk_bf16_f32 %0, %1, %2" : "=v"(lo) : "v"(pj[0]), "v"(pj[1]));
        asm("v_cvt_pk_bf16_f32 %0, %1, %2" : "=v"(hi) : "v"(pj[2]), "v"(pj[3]));
        const int sel = (4 * f + g) ^ c3;
        *reinterpret_cast<uint2*>(&pw[fr * 36 + sel * 2]) = make_uint2(lo, hi);
      }
    }
    // cross-lane LDS dep within the wave: drain DS writes, pin reads after
    asm volatile("s_waitcnt lgkmcnt(0)" ::: "memory");
    __builtin_amdgcn_sched_barrier(0);
    bf16x8 pa0 = *reinterpret_cast<const bf16x8*>(&pw[fr * 36 + ((sA ^ c3) * 2)]);
    bf16x8 pa1 = *reinterpret_cast<const bf16x8*>(&pw[fr * 36 + (((8 + sA) ^ c3) * 2)]);

    // ---- PV (+ ones-row l-sum in dt=5), swizzled V reads ----
    const u16* vb = V_lds[cur];
    #pragma unroll
    for (int dt = 0; dt < 6; ++dt) {
      const int row = dt * 16 + fr;
      const u16* vp = vb + row * 64;
      bf16x8 vb0 = *reinterpret_cast<const bf16x8*>(vp + ((g ^ (fr & 7)) * 8));
      bf16x8 vb1 = *reinterpret_cast<const bf16x8*>(vp + ((((4 + g)) ^ (fr & 7)) * 8));
      acc[dt] = __builtin_amdgcn_mfma_f32_16x16x32_bf16(pa0, vb0, acc[dt], 0, 0, 0);
      acc[dt] = __builtin_amdgcn_mfma_f32_16x16x32_bf16(pa1, vb1, acc[dt], 0, 0, 0);
    }

    __syncthreads();
  }
  #undef ASTAGE
  #undef SSTAGE

  // ---- epilogue (acc[dt][j] = O[q-row g*4+j][d=dt*16+fr]) ----
  #pragma unroll
  for (int j = 0; j < 4; ++j) {
    const float lsum = __shfl(acc[5][j], l & 48);  // lane (g, fr=0): ones-row sum
    const float il = (lsum > 0.f) ? 1.0f / lsum : 0.f;
    const int row = t0 + w * 16 + g * 4 + j;
    #pragma unroll
    for (int dt = 0; dt < 5; ++dt)
      attn_bf[(size_t)row * EMB + h * HD + dt * 16 + fr] = f2bf(acc[dt][j] * il);
  }
}

extern "C" void kernel_launch(void* const* d_in, const int* in_sizes, int n_in,
                              void* d_out, int out_size, void* d_ws, size_t ws_size,
                              hipStream_t stream) {
  const float* hidden = (const float*)d_in[0];
  const int*   cu     = (const int*)d_in[1];
  const float* rope   = (const float*)d_in[2];
  const float* w_qkv  = (const float*)d_in[3];
  const float* w_o    = (const float*)d_in[4];
  const float* qw     = (const float*)d_in[5];
  const float* kw     = (const float*)d_in[6];
  float* out = (float*)d_out;

  const int T = in_sizes[0] / EMB;   // 4096
  const int n_seq = in_sizes[1] - 1; // 8

  // workspace (~37MB): qkv_bf | hid_bf(=attn_bf alias) | wqkv_bf | wo_bf | v_t | seg
  u16* qkv_bf  = (u16*)d_ws;
  u16* hid_bf  = qkv_bf + (size_t)T * QKV_ROW;
  u16* attn_bf = hid_bf;  // alias: hid_bf dead after gemm_qkv
  u16* wqkv_bf = hid_bf + (size_t)T * EMB;
  u16* wo_bf   = wqkv_bf + (size_t)QKV_ROW * EMB;
  u16* v_t     = wo_bf + (size_t)EMB * EMB;           // [320][4096] + slack
  int* segb    = (int*)(v_t + (size_t)320 * 4096 + 64);

  const int nq_hid = T * EMB / 4, nq_wqkv = QKV_ROW * EMB / 4, nq_wo = EMB * EMB / 4;
  const int nq_tot = nq_hid + nq_wqkv + nq_wo;
  prep_kernel<<<(nq_tot + 255) / 256, 256, 0, stream>>>(
      hidden, w_qkv, w_o, cu, n_seq, T, hid_bf, wqkv_bf, wo_bf, segb,
      nq_hid, nq_wqkv, nq_wo);

  // qkv[:,0:1600] + v_t = hidden @ w_qkv^T  (V columns transposed; grid 960 % 8 == 0)
  {
    const int gx = QKV_ROW / 64, nwg = gx * (T / 128);  // 30 * 32 = 960
    gemm_bf16<u16, true><<<nwg, 256, 0, stream>>>(hid_bf, wqkv_bf, qkv_bf, v_t,
                                                  T, QKV_ROW, EMB, QKV_ROW, gx, nwg);
  }
  norm_rope_bf<<<T, 320, 0, stream>>>(qkv_bf, rope, qw, kw);
  attn_v7<<<dim3(T / QT, H_Q), 512, 0, stream>>>(qkv_bf, v_t, segb, cu, T, attn_bf);
  // out = attn @ w_o^T  (fp32 out; grid 640 % 8 == 0)
  {
    const int gx = EMB / 64, nwg = gx * (T / 128);  // 20 * 32 = 640
    gemm_bf16<float, false><<<nwg, 256, 0, stream>>>(attn_bf, wo_bf, out, nullptr,
                                                     T, EMB, EMB, EMB, gx, nwg);
  }
}

// Round 15
// 113.994 us; speedup vs baseline: 1.1718x; 1.0097x over previous
//
#include <hip/hip_runtime.h>
#include <hip/hip_bf16.h>

#define H_Q 16
#define H_KV 4
#define HD 80
#define QKV_ROW 1920   // qkv buffer row stride (cols 0..1599 live: Q,K)
#define K_OFF 1280     // 16*80
#define EMB 1280
#define QT 256         // query tile rows (16 waves): halves K/V staging per MFMA
#define KC 64          // k/v chunk rows
#define KROW 80        // K_lds row stride (u16), unpadded
#define VTS 4096       // v_t row stride (tokens)

typedef unsigned short u16;
typedef unsigned int u32;
typedef __attribute__((ext_vector_type(8))) short bf16x8;
typedef __attribute__((ext_vector_type(4))) float f32x4;

__device__ inline u16 f2bf(float f) {
  unsigned u = __float_as_uint(f);
  unsigned r = (u + 0x7FFFu + ((u >> 16) & 1u)) >> 16;
  return (u16)r;
}
__device__ inline float bf2f(u16 v) { return __uint_as_float(((unsigned)v) << 16); }

__device__ inline void cvt4(const float* __restrict__ in, u16* __restrict__ out, int q) {
  float4 v = *reinterpret_cast<const float4*>(in + q * 4);
  ushort4 o;
  o.x = f2bf(v.x); o.y = f2bf(v.y); o.z = f2bf(v.z); o.w = f2bf(v.w);
  *reinterpret_cast<ushort4*>(out + q * 4) = o;
}

// ---------------- fused prep: 3x fp32->bf16 + seg ids ----------------
__global__ __launch_bounds__(256) void prep_kernel(const float* __restrict__ hidden,
                                                   const float* __restrict__ w_qkv,
                                                   const float* __restrict__ w_o,
                                                   const int* __restrict__ cu, int n_seq, int T,
                                                   u16* __restrict__ hid_bf,
                                                   u16* __restrict__ wqkv_bf,
                                                   u16* __restrict__ wo_bf,
                                                   int* __restrict__ seg,
                                                   int nq_hid, int nq_wqkv, int nq_wo) {
  const int i = blockIdx.x * 256 + threadIdx.x;
  if (i < T) {
    int s = 0;
    for (int k = 1; k <= n_seq; ++k) s += (i >= cu[k]) ? 1 : 0;
    seg[i] = s;
  }
  int q = i;
  if (q < nq_hid) { cvt4(hidden, hid_bf, q); return; }
  q -= nq_hid;
  if (q < nq_wqkv) { cvt4(w_qkv, wqkv_bf, q); return; }
  q -= nq_wqkv;
  if (q < nq_wo) cvt4(w_o, wo_bf, q);
}

// ---------------- bf16 MFMA GEMM: C[M,N] = A[M,K] * B[N,K]^T ----------------
// 128x64 tile, BK=64 (16 MFMA + 12 ds_read per barrier-pair; 20 iters at K=1280).
// 2 LDS buffers, prefetch distance 1, counted vmcnt(6). 8-slot XOR swizzle
// (phys = log ^ (row&7)): source col pre-swizzled, LDS dest linear (T21), reads
// apply same XOR -> 2 lanes/bank (conflict-free, verified R14: SQ_LDS_BANK_CONFLICT=0).
// VSPLIT: column-fragments with col>=1600 are written TRANSPOSED to vt[col-1600][row].
template <typename OUT, bool VSPLIT>
__global__ __launch_bounds__(256) void gemm_bf16(const u16* __restrict__ A,
                                                 const u16* __restrict__ B,
                                                 OUT* __restrict__ C,
                                                 u16* __restrict__ vt,
                                                 int M, int N, int K, int ldc,
                                                 int gx, int nwg) {
  __shared__ u16 As[2][128 * 64];
  __shared__ u16 Bs[2][64 * 64];
  const int tid = threadIdx.x;
  const int id = blockIdx.x;
  const int sw = (id & 7) * (nwg >> 3) + (id >> 3);  // nwg % 8 == 0 guaranteed
  const int bm = (sw / gx) * 128;
  const int bn = (sw % gx) * 64;
  const int w = tid >> 6;
  const int l = tid & 63;
  const int wr = (w >> 1) * 64, wc = (w & 1) * 32;
  const int fr = l & 15;
  const int fq = l >> 4;
  const int srow = tid >> 3;                              // staging row within 32-row group
  const int scol = ((tid & 7) ^ ((tid >> 3) & 7)) * 8;    // pre-swizzled source k-slot

  f32x4 acc[4][2];
  #pragma unroll
  for (int mi = 0; mi < 4; ++mi)
    #pragma unroll
    for (int ni = 0; ni < 2; ++ni) acc[mi][ni] = (f32x4){0.f, 0.f, 0.f, 0.f};

  // 6 global_load_lds per STAGE (4 for A 128x64, 2 for B 64x64); dest linear tid*16B
  #define GSTAGE(buf, k0)                                                             \
    do {                                                                              \
      _Pragma("unroll")                                                               \
      for (int it = 0; it < 4; ++it) {                                                \
        const u16* ga = A + (size_t)(bm + it * 32 + srow) * K + (k0) + scol;          \
        __builtin_amdgcn_global_load_lds(                                             \
            (const __attribute__((address_space(1))) unsigned int*)ga,                \
            (__attribute__((address_space(3))) unsigned int*)&As[buf][it * 2048 + tid * 8], 16, 0, 0); \
      }                                                                               \
      _Pragma("unroll")                                                               \
      for (int it = 0; it < 2; ++it) {                                                \
        const u16* gb = B + (size_t)(bn + it * 32 + srow) * K + (k0) + scol;          \
        __builtin_amdgcn_global_load_lds(                                             \
            (const __attribute__((address_space(1))) unsigned int*)gb,                \
            (__attribute__((address_space(3))) unsigned int*)&Bs[buf][it * 2048 + tid * 8], 16, 0, 0); \
      }                                                                               \
    } while (0)

  const int nt = K >> 6;  // K=1280 -> 20
  GSTAGE(0, 0);

  for (int t = 0; t < nt; ++t) {
    const int cur = t & 1;
    if (t + 1 < nt) {
      GSTAGE(cur ^ 1, (t + 1) * 64);      // buf read at t-1; protected by t-1's end barrier
      asm volatile("s_waitcnt vmcnt(6)" ::: "memory");   // own stage done, next in flight
    } else {
      asm volatile("s_waitcnt vmcnt(0)" ::: "memory");
    }
    __builtin_amdgcn_s_barrier();           // all waves: buf[cur] DMA complete
    __builtin_amdgcn_sched_barrier(0);      // pin ds_reads after the wait

    bf16x8 af[4][2], bfr[2][2];
    #pragma unroll
    for (int mi = 0; mi < 4; ++mi)
      #pragma unroll
      for (int kk = 0; kk < 2; ++kk) {
        const int ps = ((kk * 4 + fq) ^ (fr & 7)) * 8;   // swizzled physical slot
        af[mi][kk] = *reinterpret_cast<const bf16x8*>(&As[cur][(wr + mi * 16 + fr) * 64 + ps]);
      }
    #pragma unroll
    for (int ni = 0; ni < 2; ++ni)
      #pragma unroll
      for (int kk = 0; kk < 2; ++kk) {
        const int ps = ((kk * 4 + fq) ^ (fr & 7)) * 8;
        bfr[ni][kk] = *reinterpret_cast<const bf16x8*>(&Bs[cur][(wc + ni * 16 + fr) * 64 + ps]);
      }
    __builtin_amdgcn_s_setprio(1);
    #pragma unroll
    for (int kk = 0; kk < 2; ++kk)
      #pragma unroll
      for (int mi = 0; mi < 4; ++mi)
        #pragma unroll
        for (int ni = 0; ni < 2; ++ni)
          acc[mi][ni] = __builtin_amdgcn_mfma_f32_16x16x32_bf16(af[mi][kk], bfr[ni][kk],
                                                               acc[mi][ni], 0, 0, 0);
    __builtin_amdgcn_s_setprio(0);

    __builtin_amdgcn_sched_barrier(0);
    __builtin_amdgcn_s_barrier();           // all waves' reads of buf[cur] done
  }
  #undef GSTAGE

  #pragma unroll
  for (int mi = 0; mi < 4; ++mi)
    #pragma unroll
    for (int ni = 0; ni < 2; ++ni) {
      const int col = bn + wc + ni * 16 + fr;
      const int row0 = bm + wr + mi * 16 + fq * 4;
      if (VSPLIT && col >= 1600) {
        // transposed V write: vt[col-1600][row0..row0+3] (8B packed store)
        ushort4 o;
        o.x = f2bf(acc[mi][ni][0]); o.y = f2bf(acc[mi][ni][1]);
        o.z = f2bf(acc[mi][ni][2]); o.w = f2bf(acc[mi][ni][3]);
        *reinterpret_cast<ushort4*>(&vt[(size_t)(col - 1600) * VTS + row0]) = o;
      } else {
        #pragma unroll
        for (int j = 0; j < 4; ++j) {
          if constexpr (sizeof(OUT) == 2)
            C[(size_t)(row0 + j) * ldc + col] = f2bf(acc[mi][ni][j]);
          else
            C[(size_t)(row0 + j) * ldc + col] = acc[mi][ni][j];
        }
      }
    }
}

// ---------------- per-token RMSNorm + RoPE ----------------
// grid = T, block 320 (5 waves); wave w handles heads w*4 .. w*4+3.
// NOTE: the rotate-half read xs[w][d +/- 40] is a CROSS-LANE dependency through
// LDS; __syncthreads() between write and read is REQUIRED (R6/R7 failure).
__global__ __launch_bounds__(320) void norm_rope_bf(u16* __restrict__ qkv,
                                                    const float* __restrict__ freqs,
                                                    const float* __restrict__ qw,
                                                    const float* __restrict__ kw) {
  const int t = blockIdx.x;
  const int tid = threadIdx.x;
  __shared__ float cs[HD], sn[HD];
  __shared__ float wq[HD], wk[HD];
  __shared__ float xs[5][HD];
  if (tid < HD) {
    const float f = freqs[(size_t)t * HD + tid];
    cs[tid] = __cosf(f);
    sn[tid] = __sinf(f);
    wq[tid] = qw[tid];
    wk[tid] = kw[tid];
  }
  __syncthreads();
  const int w = tid >> 6, lane = tid & 63;
  #pragma unroll
  for (int i = 0; i < 4; ++i) {
    const int hh = w * 4 + i;
    const bool is_q = (hh < H_Q);
    u16* x = qkv + (size_t)t * QKV_ROW + (is_q ? hh * HD : K_OFF + (hh - H_Q) * HD);
    const float* wt = is_q ? wq : wk;
    float a = bf2f(x[lane]);
    float b = (lane < HD - 64) ? bf2f(x[64 + lane]) : 0.0f;
    float ss = a * a + b * b;
    #pragma unroll
    for (int off = 32; off; off >>= 1) ss += __shfl_down(ss, off);
    ss = __shfl(ss, 0);
    const float inv = rsqrtf(ss * (1.0f / HD) + 1e-6f);
    xs[w][lane] = a * inv * wt[lane];
    if (lane < HD - 64) xs[w][64 + lane] = b * inv * wt[64 + lane];
    __syncthreads();  // REQUIRED: cross-lane LDS dep
    {
      const int d = lane;
      const float rot = (d < HD / 2) ? -xs[w][d + HD / 2] : xs[w][d - HD / 2];
      x[d] = f2bf(xs[w][d] * cs[d] + rot * sn[d]);
    }
    if (lane < HD - 64) {
      const int d = 64 + lane;
      const float rot = (d < HD / 2) ? -xs[w][d + HD / 2] : xs[w][d - HD / 2];
      x[d] = f2bf(xs[w][d] * cs[d] + rot * sn[d]);
    }
    __syncthreads();  // all reads done before next iteration's writes
  }
}

// ---------------- MFMA flash attention v8: QT=256, 16 waves ----------------
// grid (T/QT, 16) = 256 blocks (1/CU, 16 waves). Same per-wave math as v7:
// swapped QK^T, in-register P via cvt_pk + per-wave LDS exchange, ones-row l-sum,
// no online max (RMSNorm bounds |S*scale| <= ~9.0). K/V staging per chunk is
// constant while MFMA per chunk doubles vs QT=128 -> staging cost halved.
__global__ __launch_bounds__(1024) void attn_v8(const u16* __restrict__ qkv,
                                                const u16* __restrict__ vt,
                                                const int* __restrict__ seg,
                                                const int* __restrict__ cu,
                                                int T,
                                                u16* __restrict__ attn_bf) {
  __shared__ u16 K_lds[2][KC * KROW + 16];  // +16 slack (zeroed) for g=3 overread on row 63
  __shared__ u16 V_lds[2][96 * 64];         // V^T rows 0..79 staged; 80=ones, 81..95=0
  __shared__ u32 Pw[16][16 * 36];           // per-wave P exchange: fr stride 36 u32
  __shared__ int ksegs[2][KC];

  const int t0 = blockIdx.x * QT;
  const int h = blockIdx.y;
  const int kvh = h >> 2;
  const int tid = threadIdx.x;
  const int w = tid >> 6, l = tid & 63;
  const int g = l >> 4, fr = l & 15;

  for (int i = tid; i < 2 * 16 * 32; i += 1024) {
    const int b = i >> 9, r = (i >> 5) & 15, c = i & 31;
    ((u32*)V_lds[b])[(80 + r) * 32 + c] = (r == 0) ? 0x3f803f80u : 0u;
  }
  if (tid < 16) { K_lds[0][KC * KROW + tid] = 0; K_lds[1][KC * KROW + tid] = 0; }

  const int s0_ = seg[t0], s1_ = seg[t0 + QT - 1];
  const int kbeg = cu[s0_], kend = cu[s1_ + 1];
  const bool fast = (s0_ == s1_) && (((kend - kbeg) & (KC - 1)) == 0) && ((kbeg & 7) == 0);

  // Q fragments (registers). head-dim padded 80->96 with zeros.
  const int qrow = t0 + w * 16 + fr;
  const u16* qp = qkv + (size_t)qrow * QKV_ROW + h * HD;
  bf16x8 qa0 = *reinterpret_cast<const bf16x8*>(qp + g * 8);
  bf16x8 qa1 = *reinterpret_cast<const bf16x8*>(qp + 32 + g * 8);
  bf16x8 qa2 = (g < 2) ? *reinterpret_cast<const bf16x8*>(qp + 64 + g * 8)
                       : (bf16x8)(short)0;
  const int qsgl = seg[qrow];  // swapped layout: lane's q-row is fr-based

  f32x4 acc[6];
  #pragma unroll
  for (int dt = 0; dt < 6; ++dt) acc[dt] = (f32x4){0.f, 0.f, 0.f, 0.f};
  const float C2 = 0.16130010464f;  // (1/sqrt(80)) * log2(e)

  #define ASTAGE(nb, cc)                                                               \
    do {                                                                               \
      for (int i = tid; i < 640; i += 1024) {                                          \
        const int kr = i / 10, kc_ = i - kr * 10;                                      \
        const u16* gk = qkv + (size_t)((cc) + kr) * QKV_ROW + K_OFF + kvh * HD + kc_ * 8; \
        __builtin_amdgcn_global_load_lds(                                              \
            (const __attribute__((address_space(1))) u32*)gk,                          \
            (__attribute__((address_space(3))) u32*)&K_lds[nb][i * 8], 16, 0, 0);      \
        const int vr = i >> 3, vs = i & 7;                                             \
        const u16* gv = vt + (size_t)(kvh * HD + vr) * VTS + (cc) + ((vs ^ (vr & 7)) * 8); \
        __builtin_amdgcn_global_load_lds(                                              \
            (const __attribute__((address_space(1))) u32*)gv,                          \
            (__attribute__((address_space(3))) u32*)&V_lds[nb][i * 8], 16, 0, 0);      \
      }                                                                                \
    } while (0)

  #define SSTAGE(nb, cc)                                                               \
    do {                                                                               \
      for (int i = tid; i < KC * 40; i += 1024) {                                      \
        const int r = i / 40, ccc = i - r * 40;                                        \
        u32 v = 0;                                                                     \
        if ((cc) + r < kend)                                                           \
          v = reinterpret_cast<const u32*>(qkv + (size_t)((cc) + r) * QKV_ROW + K_OFF + kvh * HD)[ccc]; \
        ((u32*)K_lds[nb])[i] = v;                                                      \
      }                                                                                \
      for (int i = tid; i < HD * KC; i += 1024) {                                      \
        const int vr = i >> 6, k = i & 63;                                             \
        u16 v = 0;                                                                     \
        if ((cc) + k < kend)                                                           \
          v = vt[(size_t)(kvh * HD + vr) * VTS + (cc) + k];                            \
        V_lds[nb][vr * 64 + (((k >> 3) ^ (vr & 7)) * 8) + (k & 7)] = v;                \
      }                                                                                \
      if (tid < KC) ksegs[nb][tid] = ((cc) + tid < kend) ? seg[(cc) + tid] : -1;       \
    } while (0)

  if (fast) ASTAGE(0, kbeg); else SSTAGE(0, kbeg);
  __syncthreads();

  const int c3 = (fr & 3) << 2;       // pair-granularity XOR swizzle key
  u32* pw = &Pw[w][0];
  const int sA = 4 * (g >> 1) + 2 * (g & 1);

  int nb = 0;
  for (int c = kbeg; c < kend; c += KC) {
    const int cur = nb;
    nb ^= 1;
    if (c + KC < kend) {
      if (fast) ASTAGE(nb, c + KC); else SSTAGE(nb, c + KC);
    }

    // ---- S^T = K Q^T (swapped operands) ----
    const u16* kb = K_lds[cur];
    f32x4 sacc[4];
    #pragma unroll
    for (int f = 0; f < 4; ++f) {
      const u16* kp = kb + (f * 16 + fr) * KROW;
      bf16x8 b0 = *reinterpret_cast<const bf16x8*>(kp + g * 8);
      bf16x8 b1 = *reinterpret_cast<const bf16x8*>(kp + 32 + g * 8);
      bf16x8 b2 = *reinterpret_cast<const bf16x8*>(kp + 64 + g * 8);
      f32x4 s = (f32x4){0.f, 0.f, 0.f, 0.f};
      s = __builtin_amdgcn_mfma_f32_16x16x32_bf16(b0, qa0, s, 0, 0, 0);
      s = __builtin_amdgcn_mfma_f32_16x16x32_bf16(b1, qa1, s, 0, 0, 0);
      s = __builtin_amdgcn_mfma_f32_16x16x32_bf16(b2, qa2, s, 0, 0, 0);
      sacc[f] = s;  // sacc[f][j] = S[k = c + f*16 + g*4 + j][q = fr]
    }

    // ---- P = exp2(S*C2), cvt_pk to bf16, wave-local LDS exchange ----
    if (fast) {
      #pragma unroll
      for (int f = 0; f < 4; ++f) {
        const float p0 = __builtin_exp2f(sacc[f][0] * C2);
        const float p1 = __builtin_exp2f(sacc[f][1] * C2);
        const float p2 = __builtin_exp2f(sacc[f][2] * C2);
        const float p3 = __builtin_exp2f(sacc[f][3] * C2);
        u32 lo, hi;
        asm("v_cvt_pk_bf16_f32 %0, %1, %2" : "=v"(lo) : "v"(p0), "v"(p1));
        asm("v_cvt_pk_bf16_f32 %0, %1, %2" : "=v"(hi) : "v"(p2), "v"(p3));
        const int sel = (4 * f + g) ^ c3;
        *reinterpret_cast<uint2*>(&pw[fr * 36 + sel * 2]) = make_uint2(lo, hi);
      }
    } else {
      #pragma unroll
      for (int f = 0; f < 4; ++f) {
        float pj[4];
        #pragma unroll
        for (int j = 0; j < 4; ++j) {
          const int kk = f * 16 + g * 4 + j;
          float e = sacc[f][j] * C2;
          if (qsgl != ksegs[cur][kk]) e = -1e30f;  // exp2(-inf) = 0
          pj[j] = __builtin_exp2f(e);
        }
        u32 lo, hi;
        asm("v_cvt_pk_bf16_f32 %0, %1, %2" : "=v"(lo) : "v"(pj[0]), "v"(pj[1]));
        asm("v_cvt_pk_bf16_f32 %0, %1, %2" : "=v"(hi) : "v"(pj[2]), "v"(pj[3]));
        const int sel = (4 * f + g) ^ c3;
        *reinterpret_cast<uint2*>(&pw[fr * 36 + sel * 2]) = make_uint2(lo, hi);
      }
    }
    // cross-lane LDS dep within the wave: drain DS writes, pin reads after
    asm volatile("s_waitcnt lgkmcnt(0)" ::: "memory");
    __builtin_amdgcn_sched_barrier(0);
    bf16x8 pa0 = *reinterpret_cast<const bf16x8*>(&pw[fr * 36 + ((sA ^ c3) * 2)]);
    bf16x8 pa1 = *reinterpret_cast<const bf16x8*>(&pw[fr * 36 + (((8 + sA) ^ c3) * 2)]);

    // ---- PV (+ ones-row l-sum in dt=5), swizzled V reads ----
    const u16* vb = V_lds[cur];
    #pragma unroll
    for (int dt = 0; dt < 6; ++dt) {
      const int row = dt * 16 + fr;
      const u16* vp = vb + row * 64;
      bf16x8 vb0 = *reinterpret_cast<const bf16x8*>(vp + ((g ^ (fr & 7)) * 8));
      bf16x8 vb1 = *reinterpret_cast<const bf16x8*>(vp + ((((4 + g)) ^ (fr & 7)) * 8));
      acc[dt] = __builtin_amdgcn_mfma_f32_16x16x32_bf16(pa0, vb0, acc[dt], 0, 0, 0);
      acc[dt] = __builtin_amdgcn_mfma_f32_16x16x32_bf16(pa1, vb1, acc[dt], 0, 0, 0);
    }

    __syncthreads();
  }
  #undef ASTAGE
  #undef SSTAGE

  // ---- epilogue (acc[dt][j] = O[q-row g*4+j][d=dt*16+fr]) ----
  #pragma unroll
  for (int j = 0; j < 4; ++j) {
    const float lsum = __shfl(acc[5][j], l & 48);  // lane (g, fr=0): ones-row sum
    const float il = (lsum > 0.f) ? 1.0f / lsum : 0.f;
    const int row = t0 + w * 16 + g * 4 + j;
    #pragma unroll
    for (int dt = 0; dt < 5; ++dt)
      attn_bf[(size_t)row * EMB + h * HD + dt * 16 + fr] = f2bf(acc[dt][j] * il);
  }
}

extern "C" void kernel_launch(void* const* d_in, const int* in_sizes, int n_in,
                              void* d_out, int out_size, void* d_ws, size_t ws_size,
                              hipStream_t stream) {
  const float* hidden = (const float*)d_in[0];
  const int*   cu     = (const int*)d_in[1];
  const float* rope   = (const float*)d_in[2];
  const float* w_qkv  = (const float*)d_in[3];
  const float* w_o    = (const float*)d_in[4];
  const float* qw     = (const float*)d_in[5];
  const float* kw     = (const float*)d_in[6];
  float* out = (float*)d_out;

  const int T = in_sizes[0] / EMB;   // 4096
  const int n_seq = in_sizes[1] - 1; // 8

  // workspace (~37MB): qkv_bf | hid_bf(=attn_bf alias) | wqkv_bf | wo_bf | v_t | seg
  u16* qkv_bf  = (u16*)d_ws;
  u16* hid_bf  = qkv_bf + (size_t)T * QKV_ROW;
  u16* attn_bf = hid_bf;  // alias: hid_bf dead after gemm_qkv
  u16* wqkv_bf = hid_bf + (size_t)T * EMB;
  u16* wo_bf   = wqkv_bf + (size_t)QKV_ROW * EMB;
  u16* v_t     = wo_bf + (size_t)EMB * EMB;           // [320][4096] + slack
  int* segb    = (int*)(v_t + (size_t)320 * 4096 + 64);

  const int nq_hid = T * EMB / 4, nq_wqkv = QKV_ROW * EMB / 4, nq_wo = EMB * EMB / 4;
  const int nq_tot = nq_hid + nq_wqkv + nq_wo;
  prep_kernel<<<(nq_tot + 255) / 256, 256, 0, stream>>>(
      hidden, w_qkv, w_o, cu, n_seq, T, hid_bf, wqkv_bf, wo_bf, segb,
      nq_hid, nq_wqkv, nq_wo);

  // qkv[:,0:1600] + v_t = hidden @ w_qkv^T  (V columns transposed; grid 960 % 8 == 0)
  {
    const int gx = QKV_ROW / 64, nwg = gx * (T / 128);  // 30 * 32 = 960
    gemm_bf16<u16, true><<<nwg, 256, 0, stream>>>(hid_bf, wqkv_bf, qkv_bf, v_t,
                                                  T, QKV_ROW, EMB, QKV_ROW, gx, nwg);
  }
  norm_rope_bf<<<T, 320, 0, stream>>>(qkv_bf, rope, qw, kw);
  attn_v8<<<dim3(T / QT, H_Q), 1024, 0, stream>>>(qkv_bf, v_t, segb, cu, T, attn_bf);
  // out = attn @ w_o^T  (fp32 out; grid 640 % 8 == 0)
  {
    const int gx = EMB / 64, nwg = gx * (T / 128);  // 20 * 32 = 640
    gemm_bf16<float, false><<<nwg, 256, 0, stream>>>(attn_bf, wo_bf, out, nullptr,
                                                     T, EMB, EMB, EMB, gx, nwg);
  }
}